// Round 2
// baseline (288.185 us; speedup 1.0000x reference)
//
#include <hip/hip_runtime.h>

// ---------------------------------------------------------------------------
// AFT local attention, fused pipeline for MI355X (gfx950)
// B=8, F=256, L=1024, H=4, D=256, MODEL=1024, WIN=128
// ---------------------------------------------------------------------------

typedef __attribute__((ext_vector_type(8))) short short8;
typedef __attribute__((ext_vector_type(4))) float f32x4;

#define MBYTE 1048576L

__device__ __forceinline__ unsigned short f2bf(float f) {
  unsigned u = __float_as_uint(f);
  unsigned r = (u + 0x7fff + ((u >> 16) & 1)) >> 16;  // RNE
  return (unsigned short)r;
}
__device__ __forceinline__ float bf2f(unsigned short s) {
  return __uint_as_float(((unsigned)s) << 16);
}

// ---- prep: Wq/Wk/Wv -> Bt[768][256] bf16 (already [d][c] = Bt layout), bias cat
__global__ void prep_weights(const float* __restrict__ Wq, const float* __restrict__ bq,
                             const float* __restrict__ Wk, const float* __restrict__ bk,
                             const float* __restrict__ Wv, const float* __restrict__ bv,
                             unsigned short* __restrict__ Btp, float* __restrict__ biascat) {
  int i = blockIdx.x * 256 + threadIdx.x;   // 768*256 exact
  int r = i >> 8, c = i & 255;
  const float* W = (r < 256) ? Wq : ((r < 512) ? Wk : Wv);
  int rr = r & 255;
  Btp[i] = f2bf(W[rr * 256 + c]);
  if (c == 0) {
    const float* bp = (r < 256) ? bq : ((r < 512) ? bk : bv);
    biascat[r] = bp[rr];
  }
}

// ---- prep: ew[t][s] = exp(w_bias masked) bf16; masked (|t-s|>127) -> exp(0)=1
__global__ void prep_ew(const float* __restrict__ wbias, unsigned short* __restrict__ ew) {
  int i = blockIdx.x * 256 + threadIdx.x;   // 1M exact
  int t = i >> 10, s = i & 1023;
  int d = t - s;
  float wb = (d >= -127 && d <= 127) ? wbias[i] : 0.0f;
  ew[i] = f2bf(__expf(wb));
}

// ---- prep: out_wT[mm][j] = bf16(out_w[j][mm])  (transpose 1024x1024)
__global__ void prep_outwT(const float* __restrict__ outw, unsigned short* __restrict__ outwT) {
  __shared__ float tle[32][33];
  int j0 = blockIdx.y * 32, m0 = blockIdx.x * 32;
  int tx = threadIdx.x;
  for (int r = threadIdx.y; r < 32; r += 8)
    tle[r][tx] = outw[(long)(j0 + r) * 1024 + m0 + tx];
  __syncthreads();
  for (int r = threadIdx.y; r < 32; r += 8)
    outwT[(long)(m0 + r) * 1024 + j0 + tx] = f2bf(tle[tx][r]);
}

// ---- x[n][c][l][h] -> xT bf16 [n][l][h][c]  (= GEMM1 A rows m=(n,l,h), k=c)
__global__ void transpose_x(const float* __restrict__ x, unsigned short* __restrict__ xT) {
  __shared__ float tle[32][33];
  int n = blockIdx.z;
  int c0 = blockIdx.y * 32, lh0 = blockIdx.x * 32;
  int tx = threadIdx.x;
  for (int r = threadIdx.y; r < 32; r += 8)
    tle[r][tx] = x[(long)n * 1048576 + (long)(c0 + r) * 4096 + lh0 + tx];
  __syncthreads();
  for (int r = threadIdx.y; r < 32; r += 8) {
    int lh = lh0 + r, c = c0 + tx;
    int l = lh >> 2, h = lh & 3;
    xT[(long)n * 1048576 + (long)l * 1024 + h * 256 + c] = f2bf(tle[tx][r]);
  }
}

// ---- ekF,vF [n][l][j](j=h*256+d) -> ekkT[n][2048][1024]: rows j = ek^T, rows 1024+j = (ek*v)^T
__global__ void transpose_ekv(const unsigned short* __restrict__ ekF,
                              const unsigned short* __restrict__ vF,
                              unsigned short* __restrict__ ekkT) {
  __shared__ unsigned short tEK[32][33];
  __shared__ unsigned short tEKV[32][33];
  int n = blockIdx.z;
  int l0 = blockIdx.y * 32, j0 = blockIdx.x * 32;
  int tx = threadIdx.x;
  for (int r = threadIdx.y; r < 32; r += 8) {
    long idx = (long)n * 1048576 + (long)(l0 + r) * 1024 + j0 + tx;
    unsigned short e = ekF[idx];
    unsigned short v = vF[idx];
    tEK[r][tx] = e;
    tEKV[r][tx] = f2bf(bf2f(e) * bf2f(v));
  }
  __syncthreads();
  for (int r = threadIdx.y; r < 32; r += 8) {
    int j = j0 + r, l = l0 + tx;
    ekkT[(long)n * 2097152 + (long)j * 1024 + l] = tEK[tx][r];
    ekkT[(long)n * 2097152 + (long)(1024 + j) * 1024 + l] = tEKV[tx][r];
  }
}

// ---------------------------------------------------------------------------
// bf16 MFMA GEMM, 128x128 tile, BK=64, global_load_lds staging (m97 structure).
// A [M][K] row-major bf16, Bt [N][K] row-major bf16 (B transposed). 4 waves,
// each wave does a 64x64 quadrant = 4x4 fragments of 16x16x32.
// EPI 1: proj epilogue (sigmoid(q)/exp(k)/v, bf16, qkv-flat layout)
// EPI 2: attention epilogue (den/num bf16, batched via z)
// EPI 3: output proj epilogue (+out_b + residual x, f32)
// ---------------------------------------------------------------------------
template <int EPI>
__global__ __launch_bounds__(256, 2) void gemm_bf16(
    const unsigned short* __restrict__ A, const unsigned short* __restrict__ Bt,
    int K, int lda, int ldb, long aBatch, long bBatch,
    const float* __restrict__ biascat,
    unsigned short* __restrict__ sq, unsigned short* __restrict__ ekF,
    unsigned short* __restrict__ vF,
    unsigned short* __restrict__ denB, unsigned short* __restrict__ numB,
    const float* __restrict__ outb, const float* __restrict__ xg,
    float* __restrict__ hbuf) {
  __shared__ unsigned short As[128 * 64];  // 16 KB
  __shared__ unsigned short Bs[128 * 64];  // 16 KB
  const int z = blockIdx.z;
  const unsigned short* Ab = A + (long)z * aBatch;
  const unsigned short* Bb = Bt + (long)z * bBatch;
  const int m0 = blockIdx.y * 128, n0 = blockIdx.x * 128;
  const int t = threadIdx.x, lane = t & 63;
  const int wrow = ((t >> 6) >> 1) * 64, wcol = ((t >> 6) & 1) * 64;

  f32x4 zero = {0.f, 0.f, 0.f, 0.f};
  f32x4 acc[4][4];
#pragma unroll
  for (int a = 0; a < 4; a++)
#pragma unroll
    for (int b = 0; b < 4; b++) acc[a][b] = zero;

  const int nK = K >> 6;
  for (int kt = 0; kt < nK; ++kt) {
    const int k0 = kt << 6;
    // stage A tile (128x64 bf16 = 16KB): linear LDS, per-lane global src
#pragma unroll
    for (int i = 0; i < 4; i++) {
      const int e = (t + i * 256) * 8;
      const int r = e >> 6, kc = e & 63;
      __builtin_amdgcn_global_load_lds(
          (const __attribute__((address_space(1))) void*)(Ab + (long)(m0 + r) * lda + k0 + kc),
          (__attribute__((address_space(3))) void*)(As + e), 16, 0, 0);
    }
#pragma unroll
    for (int i = 0; i < 4; i++) {
      const int e = (t + i * 256) * 8;
      const int r = e >> 6, kc = e & 63;
      __builtin_amdgcn_global_load_lds(
          (const __attribute__((address_space(1))) void*)(Bb + (long)(n0 + r) * ldb + k0 + kc),
          (__attribute__((address_space(3))) void*)(Bs + e), 16, 0, 0);
    }
    __syncthreads();
#pragma unroll
    for (int ks = 0; ks < 2; ++ks) {
      short8 af[4], bfv[4];
      const int kk = ks * 32 + (lane >> 4) * 8;
#pragma unroll
      for (int fm = 0; fm < 4; fm++)
        af[fm] = *(const short8*)&As[(wrow + fm * 16 + (lane & 15)) * 64 + kk];
#pragma unroll
      for (int fn = 0; fn < 4; fn++)
        bfv[fn] = *(const short8*)&Bs[(wcol + fn * 16 + (lane & 15)) * 64 + kk];
#pragma unroll
      for (int fm = 0; fm < 4; fm++)
#pragma unroll
        for (int fn = 0; fn < 4; fn++)
          acc[fm][fn] =
              __builtin_amdgcn_mfma_f32_16x16x32_bf16(af[fm], bfv[fn], acc[fm][fn], 0, 0, 0);
    }
    __syncthreads();
  }

  // epilogue: C/D mapping col=lane&15, row=(lane>>4)*4+j  [m89-verified]
#pragma unroll
  for (int fm = 0; fm < 4; fm++) {
#pragma unroll
    for (int fn = 0; fn < 4; fn++) {
#pragma unroll
      for (int j = 0; j < 4; j++) {
        const int row = m0 + wrow + fm * 16 + ((lane >> 4) * 4 + j);
        const int col = n0 + wcol + fn * 16 + (lane & 15);
        float val = acc[fm][fn][j];
        if constexpr (EPI == 1) {
          val += biascat[col];
          const int n = row >> 12, l = (row >> 2) & 1023, h = row & 3;
          const long base = (long)n * 1048576 + (long)l * 1024 + h * 256;
          if (col < 256)
            sq[base + col] = f2bf(1.0f / (1.0f + __expf(-val)));
          else if (col < 512)
            ekF[base + (col - 256)] = f2bf(__expf(val));
          else
            vF[base + (col - 512)] = f2bf(val);
        } else if constexpr (EPI == 2) {
          const long base = (long)z * 1048576 + (long)row * 1024;
          if (col < 1024)
            denB[base + col] = f2bf(val);
          else
            numB[base + (col - 1024)] = f2bf(val);
        } else {
          const int n = row >> 10, l = row & 1023;
          const int h = col >> 8, c = col & 255;
          const long idx = (long)row * 1024 + col;
          hbuf[idx] = val + outb[col] + xg[(long)n * 1048576 + (long)c * 4096 + l * 4 + h];
        }
      }
    }
  }
}

// ---- y = sigmoid(q) * num / den, bf16
__global__ void combine_y(const unsigned short* __restrict__ sq,
                          const unsigned short* __restrict__ denB,
                          const unsigned short* __restrict__ numB,
                          unsigned short* __restrict__ y) {
  const long i = (long)(blockIdx.x * 256 + threadIdx.x) * 4;
  ushort4 s = *(const ushort4*)(sq + i);
  ushort4 d = *(const ushort4*)(denB + i);
  ushort4 nu = *(const ushort4*)(numB + i);
  ushort4 r;
  r.x = f2bf(bf2f(s.x) * bf2f(nu.x) / bf2f(d.x));
  r.y = f2bf(bf2f(s.y) * bf2f(nu.y) / bf2f(d.y));
  r.z = f2bf(bf2f(s.z) * bf2f(nu.z) / bf2f(d.z));
  r.w = f2bf(bf2f(s.w) * bf2f(nu.w) / bf2f(d.w));
  *(ushort4*)(y + i) = r;
}

// ---- LayerNorm over 1024, one row per block (256 thr x float4)
__global__ __launch_bounds__(256) void ln_k(const float* __restrict__ hbuf,
                                            const float* __restrict__ g,
                                            const float* __restrict__ bb,
                                            float* __restrict__ out) {
  __shared__ float red[16];
  const int row = blockIdx.x, t = threadIdx.x;
  const float4 hv = *(const float4*)(hbuf + (long)row * 1024 + t * 4);
  float s = hv.x + hv.y + hv.z + hv.w;
  float ss = hv.x * hv.x + hv.y * hv.y + hv.z * hv.z + hv.w * hv.w;
#pragma unroll
  for (int off = 32; off > 0; off >>= 1) {
    s += __shfl_down(s, off, 64);
    ss += __shfl_down(ss, off, 64);
  }
  const int wid = t >> 6;
  if ((t & 63) == 0) {
    red[wid] = s;
    red[8 + wid] = ss;
  }
  __syncthreads();
  const float tot = red[0] + red[1] + red[2] + red[3];
  const float tss = red[8] + red[9] + red[10] + red[11];
  const float mu = tot * (1.0f / 1024.0f);
  const float var = tss * (1.0f / 1024.0f) - mu * mu;
  const float rs = rsqrtf(var + 1e-5f);
  const float4 gv = *(const float4*)(g + t * 4);
  const float4 bv = *(const float4*)(bb + t * 4);
  float4 o;
  o.x = (hv.x - mu) * rs * gv.x + bv.x;
  o.y = (hv.y - mu) * rs * gv.y + bv.y;
  o.z = (hv.z - mu) * rs * gv.z + bv.z;
  o.w = (hv.w - mu) * rs * gv.w + bv.w;
  *(float4*)(out + (long)row * 1024 + t * 4) = o;
}

// ---------------------------------------------------------------------------
extern "C" void kernel_launch(void* const* d_in, const int* in_sizes, int n_in,
                              void* d_out, int out_size, void* d_ws, size_t ws_size,
                              hipStream_t stream) {
  (void)in_sizes; (void)n_in; (void)out_size; (void)ws_size;
  const float* x     = (const float*)d_in[0];
  const float* Wq_w  = (const float*)d_in[1];
  const float* Wq_b  = (const float*)d_in[2];
  const float* Wk_w  = (const float*)d_in[3];
  const float* Wk_b  = (const float*)d_in[4];
  const float* Wv_w  = (const float*)d_in[5];
  const float* Wv_b  = (const float*)d_in[6];
  const float* wbias = (const float*)d_in[7];
  const float* outw  = (const float*)d_in[8];
  const float* outb  = (const float*)d_in[9];
  const float* lng   = (const float*)d_in[10];
  const float* lnb   = (const float*)d_in[11];
  // d_in[12] = local_mask: recomputed from indices (|t-s|<=127), not read.
  float* out = (float*)d_out;
  char* ws = (char*)d_ws;

  // workspace layout (liveness-overlapped, peak ~117 MB):
  unsigned short* sq   = (unsigned short*)(ws + 0 * MBYTE);    // 16 MB
  unsigned short* ekF  = (unsigned short*)(ws + 16 * MBYTE);   // 16 MB
  unsigned short* vF   = (unsigned short*)(ws + 32 * MBYTE);   // 16 MB
  unsigned short* xT   = (unsigned short*)(ws + 48 * MBYTE);   // 16 MB (dead after GEMM1)
  unsigned short* ekkT = (unsigned short*)(ws + 48 * MBYTE);   // 32 MB (overlays xT)
  unsigned short* denB = (unsigned short*)(ws + 80 * MBYTE);   // 16 MB
  unsigned short* numB = (unsigned short*)(ws + 96 * MBYTE);   // 16 MB
  unsigned short* Btp  = (unsigned short*)(ws + 112 * MBYTE);            // 384 KB
  float* biascat       = (float*)(ws + 112 * MBYTE + 393216);            // 3 KB (pad 4K)
  unsigned short* outwT= (unsigned short*)(ws + 112 * MBYTE + 397312);   // 2 MB
  unsigned short* ew   = (unsigned short*)(ws + 112 * MBYTE + 397312 + 2097152); // 2 MB
  unsigned short* y    = ekF;                       // reuse (ekF dead after transpose_ekv)
  float* hbuf          = (float*)(ws + 80 * MBYTE); // reuse den/num (dead after combine)

  prep_weights<<<768, 256, 0, stream>>>(Wq_w, Wq_b, Wk_w, Wk_b, Wv_w, Wv_b, Btp, biascat);
  prep_ew<<<4096, 256, 0, stream>>>(wbias, ew);
  prep_outwT<<<dim3(32, 32), dim3(32, 8), 0, stream>>>(outw, outwT);
  transpose_x<<<dim3(128, 8, 8), dim3(32, 8), 0, stream>>>(x, xT);

  // GEMM1: qkv proj  [32768x256] @ Bt[768x256]
  gemm_bf16<1><<<dim3(6, 256, 1), 256, 0, stream>>>(
      xT, Btp, 256, 256, 256, 0L, 0L,
      biascat, sq, ekF, vF, nullptr, nullptr, nullptr, nullptr, nullptr);

  transpose_ekv<<<dim3(32, 32, 8), dim3(32, 8), 0, stream>>>(ekF, vF, ekkT);

  // GEMM2: attention  per n: [1024x1024 ew] @ Bt[2048x1024 (ek|ekv)^T]
  gemm_bf16<2><<<dim3(16, 8, 8), 256, 0, stream>>>(
      ew, ekkT, 1024, 1024, 1024, 0L, 2097152L,
      nullptr, nullptr, nullptr, nullptr, denB, numB, nullptr, nullptr, nullptr);

  combine_y<<<8192, 256, 0, stream>>>(sq, denB, numB, y);

  // GEMM3: out proj  [8192x1024] @ Bt[1024x1024 out_w^T]  (+bias +residual)
  gemm_bf16<3><<<dim3(8, 64, 1), 256, 0, stream>>>(
      y, outwT, 1024, 1024, 1024, 0L, 0L,
      nullptr, nullptr, nullptr, nullptr, nullptr, nullptr, outb, x, hbuf);

  ln_k<<<8192, 256, 0, stream>>>(hbuf, lng, lnb, out);
}

// Round 4
// 251.633 us; speedup vs baseline: 1.1453x; 1.1453x over previous
//
#include <hip/hip_runtime.h>

// ---------------------------------------------------------------------------
// AFT local attention, fused pipeline for MI355X (gfx950)
// B=8, F=256, L=1024, H=4, D=256, MODEL=1024, WIN=128
// Round 3: banded GEMM2 (ew = 1 + expm1-band), colsum fused in transpose_ekv,
//          GEMM3 residual from xT (coalesced bf16).
// ---------------------------------------------------------------------------

typedef __attribute__((ext_vector_type(8))) short short8;
typedef __attribute__((ext_vector_type(4))) float f32x4;

#define MBYTE 1048576L

__device__ __forceinline__ unsigned short f2bf(float f) {
  unsigned u = __float_as_uint(f);
  unsigned r = (u + 0x7fff + ((u >> 16) & 1)) >> 16;  // RNE
  return (unsigned short)r;
}
__device__ __forceinline__ float bf2f(unsigned short s) {
  return __uint_as_float(((unsigned)s) << 16);
}

// ---- prep: Wq/Wk/Wv -> Bt[768][256] bf16 (already [d][c] = Bt layout), bias cat
__global__ void prep_weights(const float* __restrict__ Wq, const float* __restrict__ bq,
                             const float* __restrict__ Wk, const float* __restrict__ bk,
                             const float* __restrict__ Wv, const float* __restrict__ bv,
                             unsigned short* __restrict__ Btp, float* __restrict__ biascat) {
  int i = blockIdx.x * 256 + threadIdx.x;   // 768*256 exact
  int r = i >> 8, c = i & 255;
  const float* W = (r < 256) ? Wq : ((r < 512) ? Wk : Wv);
  int rr = r & 255;
  Btp[i] = f2bf(W[rr * 256 + c]);
  if (c == 0) {
    const float* bp = (r < 256) ? bq : ((r < 512) ? bk : bv);
    biascat[r] = bp[rr];
  }
}

// ---- prep: ewm1[t][s] = expm1(w_bias) inside band (|t-s|<=127), 0 outside.
// ew = 1 + ewm1 exactly; the "1" part is handled by the column-sum S.
__global__ void prep_ewm1(const float* __restrict__ wbias, unsigned short* __restrict__ ewm1) {
  int i = blockIdx.x * 256 + threadIdx.x;   // 1M exact
  int t = i >> 10, s = i & 1023;
  int d = t - s;
  float v = (d >= -127 && d <= 127) ? expm1f(wbias[i]) : 0.0f;
  ewm1[i] = f2bf(v);
}

// ---- prep: out_wT[mm][j] = bf16(out_w[j][mm])  (transpose 1024x1024)
__global__ void prep_outwT(const float* __restrict__ outw, unsigned short* __restrict__ outwT) {
  __shared__ float tle[32][33];
  int j0 = blockIdx.y * 32, m0 = blockIdx.x * 32;
  int tx = threadIdx.x;
  for (int r = threadIdx.y; r < 32; r += 8)
    tle[r][tx] = outw[(long)(j0 + r) * 1024 + m0 + tx];
  __syncthreads();
  for (int r = threadIdx.y; r < 32; r += 8)
    outwT[(long)(m0 + r) * 1024 + j0 + tx] = f2bf(tle[tx][r]);
}

// ---- zero the colsum accumulator S [8][2048] f32
__global__ void zero_S(float* __restrict__ S) {
  S[blockIdx.x * 256 + threadIdx.x] = 0.0f;
}

// ---- x[n][c][l][h] -> xT bf16 [n][l][h][c]  (= GEMM1 A rows m=(n,l,h), k=c;
//      also == _flatten(x) residual, row-major [8192][1024])
__global__ void transpose_x(const float* __restrict__ x, unsigned short* __restrict__ xT) {
  __shared__ float tle[32][33];
  int n = blockIdx.z;
  int c0 = blockIdx.y * 32, lh0 = blockIdx.x * 32;
  int tx = threadIdx.x;
  for (int r = threadIdx.y; r < 32; r += 8)
    tle[r][tx] = x[(long)n * 1048576 + (long)(c0 + r) * 4096 + lh0 + tx];
  __syncthreads();
  for (int r = threadIdx.y; r < 32; r += 8) {
    int lh = lh0 + r, c = c0 + tx;
    int l = lh >> 2, h = lh & 3;
    xT[(long)n * 1048576 + (long)l * 1024 + h * 256 + c] = f2bf(tle[tx][r]);
  }
}

// ---- ekF,vF [n][l][j] -> ekkT[n][2048][1024] (rows j = ek^T, 1024+j = (ek*v)^T)
//      + fused column-sums S[n][j2] = sum_l ekkT[n][j2][l]  (atomic partials)
__global__ void transpose_ekv(const unsigned short* __restrict__ ekF,
                              const unsigned short* __restrict__ vF,
                              unsigned short* __restrict__ ekkT,
                              float* __restrict__ S) {
  __shared__ unsigned short tEK[32][33];
  __shared__ unsigned short tEKV[32][33];
  __shared__ float red[2][8][32];
  int n = blockIdx.z;
  int l0 = blockIdx.y * 32, j0 = blockIdx.x * 32;
  int tx = threadIdx.x, ty = threadIdx.y;
  for (int r = ty; r < 32; r += 8) {
    long idx = (long)n * 1048576 + (long)(l0 + r) * 1024 + j0 + tx;
    unsigned short e = ekF[idx];
    unsigned short v = vF[idx];
    tEK[r][tx] = e;
    tEKV[r][tx] = f2bf(bf2f(e) * bf2f(v));
  }
  __syncthreads();
  for (int r = ty; r < 32; r += 8) {
    int j = j0 + r, l = l0 + tx;
    ekkT[(long)n * 2097152 + (long)j * 1024 + l] = tEK[tx][r];
    ekkT[(long)n * 2097152 + (long)(1024 + j) * 1024 + l] = tEKV[tx][r];
  }
  // colsum partials over l (first index of tEK/tEKV)
  float p0 = 0.f, p1 = 0.f;
#pragma unroll
  for (int q = 0; q < 4; q++) {
    p0 += bf2f(tEK[ty + q * 8][tx]);
    p1 += bf2f(tEKV[ty + q * 8][tx]);
  }
  red[0][ty][tx] = p0;
  red[1][ty][tx] = p1;
  __syncthreads();
  if (ty == 0) {
    float s0 = 0.f, s1 = 0.f;
#pragma unroll
    for (int q = 0; q < 8; q++) {
      s0 += red[0][q][tx];
      s1 += red[1][q][tx];
    }
    atomicAdd(&S[n * 2048 + j0 + tx], s0);
    atomicAdd(&S[n * 2048 + 1024 + j0 + tx], s1);
  }
}

// ---------------------------------------------------------------------------
// bf16 MFMA GEMM, 128x128 tile, BK=64, global_load_lds staging (m97 structure).
// A [M][K] row-major bf16, Bt [N][K] row-major bf16 (B transposed). 4 waves,
// each wave does a 64x64 quadrant = 4x4 fragments of 16x16x32.
// EPI 1: proj epilogue (sigmoid(q)/exp(k)/v, bf16, qkv-flat layout)
// EPI 2: BANDED attention epilogue (+S colsum, den/num bf16, batched via z);
//        k-tiles restricted to [m0-127, m0+254] (ewm1 = 0 outside band)
// EPI 3: output proj epilogue (+out_b + residual xT bf16, f32)
// ---------------------------------------------------------------------------
template <int EPI>
__global__ __launch_bounds__(256, 2) void gemm_bf16(
    const unsigned short* __restrict__ A, const unsigned short* __restrict__ Bt,
    int K, int lda, int ldb, long aBatch, long bBatch,
    const float* __restrict__ biascat,
    unsigned short* __restrict__ sq, unsigned short* __restrict__ ekF,
    unsigned short* __restrict__ vF,
    unsigned short* __restrict__ denB, unsigned short* __restrict__ numB,
    const float* __restrict__ Ssum,
    const float* __restrict__ outb, const unsigned short* __restrict__ xTr,
    float* __restrict__ hbuf) {
  __shared__ unsigned short As[128 * 64];  // 16 KB
  __shared__ unsigned short Bs[128 * 64];  // 16 KB
  const int z = blockIdx.z;
  const unsigned short* Ab = A + (long)z * aBatch;
  const unsigned short* Bb = Bt + (long)z * bBatch;
  const int m0 = blockIdx.y * 128, n0 = blockIdx.x * 128;
  const int t = threadIdx.x, lane = t & 63;
  const int wrow = ((t >> 6) >> 1) * 64, wcol = ((t >> 6) & 1) * 64;

  f32x4 zero = {0.f, 0.f, 0.f, 0.f};
  f32x4 acc[4][4];
#pragma unroll
  for (int a = 0; a < 4; a++)
#pragma unroll
    for (int b = 0; b < 4; b++) acc[a][b] = zero;

  int ktLo = 0, ktHi = (K >> 6) - 1;
  if constexpr (EPI == 2) {
    // band for rows t in [m0, m0+127]: s in [m0-127, m0+254]
    int sLo = m0 - 127; if (sLo < 0) sLo = 0;
    int sHi = m0 + 254; if (sHi > 1023) sHi = 1023;
    ktLo = sLo >> 6;
    ktHi = sHi >> 6;
  }
  for (int kt = ktLo; kt <= ktHi; ++kt) {
    const int k0 = kt << 6;
#pragma unroll
    for (int i = 0; i < 4; i++) {
      const int e = (t + i * 256) * 8;
      const int r = e >> 6, kc = e & 63;
      __builtin_amdgcn_global_load_lds(
          (const __attribute__((address_space(1))) void*)(Ab + (long)(m0 + r) * lda + k0 + kc),
          (__attribute__((address_space(3))) void*)(As + e), 16, 0, 0);
    }
#pragma unroll
    for (int i = 0; i < 4; i++) {
      const int e = (t + i * 256) * 8;
      const int r = e >> 6, kc = e & 63;
      __builtin_amdgcn_global_load_lds(
          (const __attribute__((address_space(1))) void*)(Bb + (long)(n0 + r) * ldb + k0 + kc),
          (__attribute__((address_space(3))) void*)(Bs + e), 16, 0, 0);
    }
    __syncthreads();
#pragma unroll
    for (int ks = 0; ks < 2; ++ks) {
      short8 af[4], bfv[4];
      const int kk = ks * 32 + (lane >> 4) * 8;
#pragma unroll
      for (int fm = 0; fm < 4; fm++)
        af[fm] = *(const short8*)&As[(wrow + fm * 16 + (lane & 15)) * 64 + kk];
#pragma unroll
      for (int fn = 0; fn < 4; fn++)
        bfv[fn] = *(const short8*)&Bs[(wcol + fn * 16 + (lane & 15)) * 64 + kk];
#pragma unroll
      for (int fm = 0; fm < 4; fm++)
#pragma unroll
        for (int fn = 0; fn < 4; fn++)
          acc[fm][fn] =
              __builtin_amdgcn_mfma_f32_16x16x32_bf16(af[fm], bfv[fn], acc[fm][fn], 0, 0, 0);
    }
    __syncthreads();
  }

  // epilogue: C/D mapping col=lane&15, row=(lane>>4)*4+j  [m89-verified]
#pragma unroll
  for (int fm = 0; fm < 4; fm++) {
#pragma unroll
    for (int fn = 0; fn < 4; fn++) {
#pragma unroll
      for (int j = 0; j < 4; j++) {
        const int row = m0 + wrow + fm * 16 + ((lane >> 4) * 4 + j);
        const int col = n0 + wcol + fn * 16 + (lane & 15);
        float val = acc[fm][fn][j];
        if constexpr (EPI == 1) {
          val += biascat[col];
          const int n = row >> 12, l = (row >> 2) & 1023, h = row & 3;
          const long base = (long)n * 1048576 + (long)l * 1024 + h * 256;
          if (col < 256)
            sq[base + col] = f2bf(1.0f / (1.0f + __expf(-val)));
          else if (col < 512)
            ekF[base + (col - 256)] = f2bf(__expf(val));
          else
            vF[base + (col - 512)] = f2bf(val);
        } else if constexpr (EPI == 2) {
          val += Ssum[z * 2048 + col];   // + sum_s 1*ek (the "1" of ew = 1+ewm1)
          const long base = (long)z * 1048576 + (long)row * 1024;
          if (col < 1024)
            denB[base + col] = f2bf(val);
          else
            numB[base + (col - 1024)] = f2bf(val);
        } else {
          const long idx = (long)row * 1024 + col;
          hbuf[idx] = val + outb[col] + bf2f(xTr[idx]);  // xT == _flatten(x)
        }
      }
    }
  }
}

// ---- y = sigmoid(q) * num / den, bf16
__global__ void combine_y(const unsigned short* __restrict__ sq,
                          const unsigned short* __restrict__ denB,
                          const unsigned short* __restrict__ numB,
                          unsigned short* __restrict__ y) {
  const long i = (long)(blockIdx.x * 256 + threadIdx.x) * 4;
  ushort4 s = *(const ushort4*)(sq + i);
  ushort4 d = *(const ushort4*)(denB + i);
  ushort4 nu = *(const ushort4*)(numB + i);
  ushort4 r;
  r.x = f2bf(bf2f(s.x) * bf2f(nu.x) / bf2f(d.x));
  r.y = f2bf(bf2f(s.y) * bf2f(nu.y) / bf2f(d.y));
  r.z = f2bf(bf2f(s.z) * bf2f(nu.z) / bf2f(d.z));
  r.w = f2bf(bf2f(s.w) * bf2f(nu.w) / bf2f(d.w));
  *(ushort4*)(y + i) = r;
}

// ---- LayerNorm over 1024, one row per block (256 thr x float4)
__global__ __launch_bounds__(256) void ln_k(const float* __restrict__ hbuf,
                                            const float* __restrict__ g,
                                            const float* __restrict__ bb,
                                            float* __restrict__ out) {
  __shared__ float red[16];
  const int row = blockIdx.x, t = threadIdx.x;
  const float4 hv = *(const float4*)(hbuf + (long)row * 1024 + t * 4);
  float s = hv.x + hv.y + hv.z + hv.w;
  float ss = hv.x * hv.x + hv.y * hv.y + hv.z * hv.z + hv.w * hv.w;
#pragma unroll
  for (int off = 32; off > 0; off >>= 1) {
    s += __shfl_down(s, off, 64);
    ss += __shfl_down(ss, off, 64);
  }
  const int wid = t >> 6;
  if ((t & 63) == 0) {
    red[wid] = s;
    red[8 + wid] = ss;
  }
  __syncthreads();
  const float tot = red[0] + red[1] + red[2] + red[3];
  const float tss = red[8] + red[9] + red[10] + red[11];
  const float mu = tot * (1.0f / 1024.0f);
  const float var = tss * (1.0f / 1024.0f) - mu * mu;
  const float rs = rsqrtf(var + 1e-5f);
  const float4 gv = *(const float4*)(g + t * 4);
  const float4 bv = *(const float4*)(bb + t * 4);
  float4 o;
  o.x = (hv.x - mu) * rs * gv.x + bv.x;
  o.y = (hv.y - mu) * rs * gv.y + bv.y;
  o.z = (hv.z - mu) * rs * gv.z + bv.z;
  o.w = (hv.w - mu) * rs * gv.w + bv.w;
  *(float4*)(out + (long)row * 1024 + t * 4) = o;
}

// ---------------------------------------------------------------------------
extern "C" void kernel_launch(void* const* d_in, const int* in_sizes, int n_in,
                              void* d_out, int out_size, void* d_ws, size_t ws_size,
                              hipStream_t stream) {
  (void)in_sizes; (void)n_in; (void)out_size; (void)ws_size;
  const float* x     = (const float*)d_in[0];
  const float* Wq_w  = (const float*)d_in[1];
  const float* Wq_b  = (const float*)d_in[2];
  const float* Wk_w  = (const float*)d_in[3];
  const float* Wk_b  = (const float*)d_in[4];
  const float* Wv_w  = (const float*)d_in[5];
  const float* Wv_b  = (const float*)d_in[6];
  const float* wbias = (const float*)d_in[7];
  const float* outw  = (const float*)d_in[8];
  const float* outb  = (const float*)d_in[9];
  const float* lng   = (const float*)d_in[10];
  const float* lnb   = (const float*)d_in[11];
  // d_in[12] = local_mask: recomputed from indices (|t-s|<=127), not read.
  float* out = (float*)d_out;
  char* ws = (char*)d_ws;

  // workspace layout (liveness-overlapped, peak ~116.5 MB):
  unsigned short* sq   = (unsigned short*)(ws + 0 * MBYTE);    // 16 MB
  unsigned short* ekF  = (unsigned short*)(ws + 16 * MBYTE);   // 16 MB (dead after t_ekv)
  unsigned short* denB = (unsigned short*)(ws + 16 * MBYTE);   // reuse (GEMM2 after t_ekv)
  unsigned short* vF   = (unsigned short*)(ws + 32 * MBYTE);   // 16 MB (dead after t_ekv)
  unsigned short* numB = (unsigned short*)(ws + 32 * MBYTE);   // reuse
  unsigned short* xT   = (unsigned short*)(ws + 48 * MBYTE);   // 16 MB (alive thru GEMM3)
  unsigned short* ekkT = (unsigned short*)(ws + 64 * MBYTE);   // 32 MB (dead after GEMM2)
  float* hbuf          = (float*)(ws + 64 * MBYTE);            // 32 MB (GEMM3 after GEMM2)
  unsigned short* y    = (unsigned short*)(ws + 96 * MBYTE);   // 16 MB
  unsigned short* Btp  = (unsigned short*)(ws + 112 * MBYTE);            // 384 KB
  float* biascat       = (float*)(ws + 112 * MBYTE + 393216);            // 3 KB (pad 4K)
  unsigned short* outwT= (unsigned short*)(ws + 112 * MBYTE + 397312);   // 2 MB
  unsigned short* ewm1 = (unsigned short*)(ws + 112 * MBYTE + 397312 + 2097152); // 2 MB
  float* Ssum          = (float*)(ws + 112 * MBYTE + 397312 + 2 * 2097152);      // 64 KB

  prep_weights<<<768, 256, 0, stream>>>(Wq_w, Wq_b, Wk_w, Wk_b, Wv_w, Wv_b, Btp, biascat);
  prep_ewm1<<<4096, 256, 0, stream>>>(wbias, ewm1);
  prep_outwT<<<dim3(32, 32), dim3(32, 8), 0, stream>>>(outw, outwT);
  zero_S<<<64, 256, 0, stream>>>(Ssum);
  transpose_x<<<dim3(128, 8, 8), dim3(32, 8), 0, stream>>>(x, xT);

  // GEMM1: qkv proj  [32768x256] @ Bt[768x256]
  gemm_bf16<1><<<dim3(6, 256, 1), 256, 0, stream>>>(
      xT, Btp, 256, 256, 256, 0L, 0L,
      biascat, sq, ekF, vF, nullptr, nullptr, nullptr, nullptr, nullptr, nullptr);

  transpose_ekv<<<dim3(32, 32, 8), dim3(32, 8), 0, stream>>>(ekF, vF, ekkT, Ssum);

  // GEMM2: banded attention  per n: [1024x1024 ewm1] @ Bt[2048x1024 (ek|ekv)^T] + S
  gemm_bf16<2><<<dim3(16, 8, 8), 256, 0, stream>>>(
      ewm1, ekkT, 1024, 1024, 1024, 0L, 2097152L,
      nullptr, nullptr, nullptr, nullptr, denB, numB, Ssum, nullptr, nullptr, nullptr);

  combine_y<<<8192, 256, 0, stream>>>(sq, denB, numB, y);

  // GEMM3: out proj  [8192x1024] @ Bt[1024x1024 out_w^T]  (+bias +residual xT)
  gemm_bf16<3><<<dim3(8, 64, 1), 256, 0, stream>>>(
      y, outwT, 1024, 1024, 1024, 0L, 0L,
      nullptr, nullptr, nullptr, nullptr, nullptr, nullptr, nullptr, outb, xT, hbuf);

  ln_k<<<8192, 256, 0, stream>>>(hbuf, lng, lnb, out);
}

// Round 9
// 247.021 us; speedup vs baseline: 1.1666x; 1.0187x over previous
//
#include <hip/hip_runtime.h>

// ---------------------------------------------------------------------------
// AFT local attention, fused pipeline for MI355X (gfx950)
// B=8, F=256, L=1024, H=4, D=256, MODEL=1024, WIN=128
// Round 5: named GEMM wrappers (profiling attribution) + XCD-aware block
//          swizzle on GEMM1/GEMM3 so same-A blocks share one XCD's L2.
// ---------------------------------------------------------------------------

typedef __attribute__((ext_vector_type(8))) short short8;
typedef __attribute__((ext_vector_type(4))) float f32x4;

#define MBYTE 1048576L

__device__ __forceinline__ unsigned short f2bf(float f) {
  unsigned u = __float_as_uint(f);
  unsigned r = (u + 0x7fff + ((u >> 16) & 1)) >> 16;  // RNE
  return (unsigned short)r;
}
__device__ __forceinline__ float bf2f(unsigned short s) {
  return __uint_as_float(((unsigned)s) << 16);
}

// ---- prep: Wq/Wk/Wv -> Bt[768][256] bf16 (already [d][c] = Bt layout), bias cat
__global__ void prep_weights(const float* __restrict__ Wq, const float* __restrict__ bq,
                             const float* __restrict__ Wk, const float* __restrict__ bk,
                             const float* __restrict__ Wv, const float* __restrict__ bv,
                             unsigned short* __restrict__ Btp, float* __restrict__ biascat) {
  int i = blockIdx.x * 256 + threadIdx.x;   // 768*256 exact
  int r = i >> 8, c = i & 255;
  const float* W = (r < 256) ? Wq : ((r < 512) ? Wk : Wv);
  int rr = r & 255;
  Btp[i] = f2bf(W[rr * 256 + c]);
  if (c == 0) {
    const float* bp = (r < 256) ? bq : ((r < 512) ? bk : bv);
    biascat[r] = bp[rr];
  }
}

// ---- prep: ewm1[t][s] = expm1(w_bias) inside band (|t-s|<=127), 0 outside.
// ew = 1 + ewm1 exactly; the "1" part is handled by the column-sum S.
__global__ void prep_ewm1(const float* __restrict__ wbias, unsigned short* __restrict__ ewm1) {
  int i = blockIdx.x * 256 + threadIdx.x;   // 1M exact
  int t = i >> 10, s = i & 1023;
  int d = t - s;
  float v = (d >= -127 && d <= 127) ? expm1f(wbias[i]) : 0.0f;
  ewm1[i] = f2bf(v);
}

// ---- prep: out_wT[mm][j] = bf16(out_w[j][mm])  (transpose 1024x1024)
__global__ void prep_outwT(const float* __restrict__ outw, unsigned short* __restrict__ outwT) {
  __shared__ float tle[32][33];
  int j0 = blockIdx.y * 32, m0 = blockIdx.x * 32;
  int tx = threadIdx.x;
  for (int r = threadIdx.y; r < 32; r += 8)
    tle[r][tx] = outw[(long)(j0 + r) * 1024 + m0 + tx];
  __syncthreads();
  for (int r = threadIdx.y; r < 32; r += 8)
    outwT[(long)(m0 + r) * 1024 + j0 + tx] = f2bf(tle[tx][r]);
}

// ---- zero the colsum accumulator S [8][2048] f32
__global__ void zero_S(float* __restrict__ S) {
  S[blockIdx.x * 256 + threadIdx.x] = 0.0f;
}

// ---- x[n][c][l][h] -> xT bf16 [n][l][h][c]  (= GEMM1 A rows m=(n,l,h), k=c;
//      also == _flatten(x) residual, row-major [8192][1024])
__global__ void transpose_x(const float* __restrict__ x, unsigned short* __restrict__ xT) {
  __shared__ float tle[32][33];
  int n = blockIdx.z;
  int c0 = blockIdx.y * 32, lh0 = blockIdx.x * 32;
  int tx = threadIdx.x;
  for (int r = threadIdx.y; r < 32; r += 8)
    tle[r][tx] = x[(long)n * 1048576 + (long)(c0 + r) * 4096 + lh0 + tx];
  __syncthreads();
  for (int r = threadIdx.y; r < 32; r += 8) {
    int lh = lh0 + r, c = c0 + tx;
    int l = lh >> 2, h = lh & 3;
    xT[(long)n * 1048576 + (long)l * 1024 + h * 256 + c] = f2bf(tle[tx][r]);
  }
}

// ---- ekF,vF [n][l][j] -> ekkT[n][2048][1024] (rows j = ek^T, 1024+j = (ek*v)^T)
//      + fused column-sums S[n][j2] = sum_l ekkT[n][j2][l]  (atomic partials)
__global__ void transpose_ekv(const unsigned short* __restrict__ ekF,
                              const unsigned short* __restrict__ vF,
                              unsigned short* __restrict__ ekkT,
                              float* __restrict__ S) {
  __shared__ unsigned short tEK[32][33];
  __shared__ unsigned short tEKV[32][33];
  __shared__ float red[2][8][32];
  int n = blockIdx.z;
  int l0 = blockIdx.y * 32, j0 = blockIdx.x * 32;
  int tx = threadIdx.x, ty = threadIdx.y;
  for (int r = ty; r < 32; r += 8) {
    long idx = (long)n * 1048576 + (long)(l0 + r) * 1024 + j0 + tx;
    unsigned short e = ekF[idx];
    unsigned short v = vF[idx];
    tEK[r][tx] = e;
    tEKV[r][tx] = f2bf(bf2f(e) * bf2f(v));
  }
  __syncthreads();
  for (int r = ty; r < 32; r += 8) {
    int j = j0 + r, l = l0 + tx;
    ekkT[(long)n * 2097152 + (long)j * 1024 + l] = tEK[tx][r];
    ekkT[(long)n * 2097152 + (long)(1024 + j) * 1024 + l] = tEKV[tx][r];
  }
  // colsum partials over l (first index of tEK/tEKV)
  float p0 = 0.f, p1 = 0.f;
#pragma unroll
  for (int q = 0; q < 4; q++) {
    p0 += bf2f(tEK[ty + q * 8][tx]);
    p1 += bf2f(tEKV[ty + q * 8][tx]);
  }
  red[0][ty][tx] = p0;
  red[1][ty][tx] = p1;
  __syncthreads();
  if (ty == 0) {
    float s0 = 0.f, s1 = 0.f;
#pragma unroll
    for (int q = 0; q < 8; q++) {
      s0 += red[0][q][tx];
      s1 += red[1][q][tx];
    }
    atomicAdd(&S[n * 2048 + j0 + tx], s0);
    atomicAdd(&S[n * 2048 + 1024 + j0 + tx], s1);
  }
}

// ---------------------------------------------------------------------------
// bf16 MFMA GEMM body, 128x128 tile, BK=64, global_load_lds staging (m97).
// A [M][K] row-major bf16, Bt [N][K] row-major bf16 (B transposed). 4 waves,
// each wave does a 64x64 quadrant = 4x4 fragments of 16x16x32.
// EPI 1: proj epilogue (sigmoid(q)/exp(k)/v, bf16, qkv-flat layout)
// EPI 2: BANDED attention epilogue (+S colsum, den/num bf16, batched via z);
//        k-tiles restricted to [m0-127, m0+254] (ewm1 = 0 outside band)
// EPI 3: output proj epilogue (+out_b + residual xT bf16, f32)
// ---------------------------------------------------------------------------
template <int EPI>
__device__ __forceinline__ void gemm_body(
    int bx, int by, int z,
    const unsigned short* __restrict__ A, const unsigned short* __restrict__ Bt,
    int K, int lda, int ldb, long aBatch, long bBatch,
    const float* __restrict__ biascat,
    unsigned short* __restrict__ sq, unsigned short* __restrict__ ekF,
    unsigned short* __restrict__ vF,
    unsigned short* __restrict__ denB, unsigned short* __restrict__ numB,
    const float* __restrict__ Ssum,
    const float* __restrict__ outb, const unsigned short* __restrict__ xTr,
    float* __restrict__ hbuf) {
  __shared__ unsigned short As[128 * 64];  // 16 KB
  __shared__ unsigned short Bs[128 * 64];  // 16 KB
  const unsigned short* Ab = A + (long)z * aBatch;
  const unsigned short* Bb = Bt + (long)z * bBatch;
  const int m0 = by * 128, n0 = bx * 128;
  const int t = threadIdx.x, lane = t & 63;
  const int wrow = ((t >> 6) >> 1) * 64, wcol = ((t >> 6) & 1) * 64;

  f32x4 zero = {0.f, 0.f, 0.f, 0.f};
  f32x4 acc[4][4];
#pragma unroll
  for (int a = 0; a < 4; a++)
#pragma unroll
    for (int b = 0; b < 4; b++) acc[a][b] = zero;

  int ktLo = 0, ktHi = (K >> 6) - 1;
  if constexpr (EPI == 2) {
    // band for rows t in [m0, m0+127]: s in [m0-127, m0+254]
    int sLo = m0 - 127; if (sLo < 0) sLo = 0;
    int sHi = m0 + 254; if (sHi > 1023) sHi = 1023;
    ktLo = sLo >> 6;
    ktHi = sHi >> 6;
  }
  for (int kt = ktLo; kt <= ktHi; ++kt) {
    const int k0 = kt << 6;
#pragma unroll
    for (int i = 0; i < 4; i++) {
      const int e = (t + i * 256) * 8;
      const int r = e >> 6, kc = e & 63;
      __builtin_amdgcn_global_load_lds(
          (const __attribute__((address_space(1))) void*)(Ab + (long)(m0 + r) * lda + k0 + kc),
          (__attribute__((address_space(3))) void*)(As + e), 16, 0, 0);
    }
#pragma unroll
    for (int i = 0; i < 4; i++) {
      const int e = (t + i * 256) * 8;
      const int r = e >> 6, kc = e & 63;
      __builtin_amdgcn_global_load_lds(
          (const __attribute__((address_space(1))) void*)(Bb + (long)(n0 + r) * ldb + k0 + kc),
          (__attribute__((address_space(3))) void*)(Bs + e), 16, 0, 0);
    }
    __syncthreads();
#pragma unroll
    for (int ks = 0; ks < 2; ++ks) {
      short8 af[4], bfv[4];
      const int kk = ks * 32 + (lane >> 4) * 8;
#pragma unroll
      for (int fm = 0; fm < 4; fm++)
        af[fm] = *(const short8*)&As[(wrow + fm * 16 + (lane & 15)) * 64 + kk];
#pragma unroll
      for (int fn = 0; fn < 4; fn++)
        bfv[fn] = *(const short8*)&Bs[(wcol + fn * 16 + (lane & 15)) * 64 + kk];
#pragma unroll
      for (int fm = 0; fm < 4; fm++)
#pragma unroll
        for (int fn = 0; fn < 4; fn++)
          acc[fm][fn] =
              __builtin_amdgcn_mfma_f32_16x16x32_bf16(af[fm], bfv[fn], acc[fm][fn], 0, 0, 0);
    }
    __syncthreads();
  }

  // epilogue: C/D mapping col=lane&15, row=(lane>>4)*4+j  [m89-verified]
#pragma unroll
  for (int fm = 0; fm < 4; fm++) {
#pragma unroll
    for (int fn = 0; fn < 4; fn++) {
#pragma unroll
      for (int j = 0; j < 4; j++) {
        const int row = m0 + wrow + fm * 16 + ((lane >> 4) * 4 + j);
        const int col = n0 + wcol + fn * 16 + (lane & 15);
        float val = acc[fm][fn][j];
        if constexpr (EPI == 1) {
          val += biascat[col];
          const int n = row >> 12, l = (row >> 2) & 1023, h = row & 3;
          const long base = (long)n * 1048576 + (long)l * 1024 + h * 256;
          if (col < 256)
            sq[base + col] = f2bf(1.0f / (1.0f + __expf(-val)));
          else if (col < 512)
            ekF[base + (col - 256)] = f2bf(__expf(val));
          else
            vF[base + (col - 512)] = f2bf(val);
        } else if constexpr (EPI == 2) {
          val += Ssum[z * 2048 + col];   // + sum_s 1*ek (the "1" of ew = 1+ewm1)
          const long base = (long)z * 1048576 + (long)row * 1024;
          if (col < 1024)
            denB[base + col] = f2bf(val);
          else
            numB[base + (col - 1024)] = f2bf(val);
        } else {
          const long idx = (long)row * 1024 + col;
          hbuf[idx] = val + outb[col] + bf2f(xTr[idx]);  // xT == _flatten(x)
        }
      }
    }
  }
}

// GEMM1: grid (6,256). XCD swizzle: all 6 n-blocks of one m0 share bid%8 class
// (same XCD L2) so the A row-panel is fetched from HBM once per XCD, not 6x.
// bijection: bid=[0,1536) -> c=bid&7, q=bid>>3, bx=q%6, by=c+8*(q/6).
__global__ __launch_bounds__(256, 2) void gemm1_qkv(
    const unsigned short* __restrict__ A, const unsigned short* __restrict__ Bt,
    const float* __restrict__ biascat,
    unsigned short* __restrict__ sq, unsigned short* __restrict__ ekF,
    unsigned short* __restrict__ vF) {
  int bid = blockIdx.x + 6 * blockIdx.y;
  int c = bid & 7, q = bid >> 3;
  int bx = q % 6, by = c + 8 * (q / 6);
  gemm_body<1>(bx, by, 0, A, Bt, 256, 256, 256, 0L, 0L,
               biascat, sq, ekF, vF, nullptr, nullptr, nullptr, nullptr, nullptr, nullptr);
}

// GEMM2: banded attention, natural mapping (A is 2MB L2-resident everywhere).
__global__ __launch_bounds__(256, 2) void gemm2_attn(
    const unsigned short* __restrict__ A, const unsigned short* __restrict__ Bt,
    unsigned short* __restrict__ denB, unsigned short* __restrict__ numB,
    const float* __restrict__ Ssum) {
  gemm_body<2>(blockIdx.x, blockIdx.y, blockIdx.z, A, Bt, 1024, 1024, 1024, 0L, 2097152L,
               nullptr, nullptr, nullptr, nullptr, denB, numB, Ssum, nullptr, nullptr, nullptr);
}

// GEMM3: grid (8,64). Swizzle: 8 n-blocks of one m0 share bid%8 class.
// bijection: bid=[0,512) -> c=bid&7, q=bid>>3, bx=q&7, by=8*c+(q>>3).
__global__ __launch_bounds__(256, 2) void gemm3_out(
    const unsigned short* __restrict__ A, const unsigned short* __restrict__ Bt,
    const float* __restrict__ outb, const unsigned short* __restrict__ xTr,
    float* __restrict__ hbuf) {
  int bid = blockIdx.x + 8 * blockIdx.y;
  int c = bid & 7, q = bid >> 3;
  int bx = q & 7, by = 8 * c + (q >> 3);
  gemm_body<3>(bx, by, 0, A, Bt, 1024, 1024, 1024, 0L, 0L,
               nullptr, nullptr, nullptr, nullptr, nullptr, nullptr, nullptr, outb, xTr, hbuf);
}

// ---- y = sigmoid(q) * num / den, bf16
__global__ void combine_y(const unsigned short* __restrict__ sq,
                          const unsigned short* __restrict__ denB,
                          const unsigned short* __restrict__ numB,
                          unsigned short* __restrict__ y) {
  const long i = (long)(blockIdx.x * 256 + threadIdx.x) * 4;
  ushort4 s = *(const ushort4*)(sq + i);
  ushort4 d = *(const ushort4*)(denB + i);
  ushort4 nu = *(const ushort4*)(numB + i);
  ushort4 r;
  r.x = f2bf(bf2f(s.x) * bf2f(nu.x) / bf2f(d.x));
  r.y = f2bf(bf2f(s.y) * bf2f(nu.y) / bf2f(d.y));
  r.z = f2bf(bf2f(s.z) * bf2f(nu.z) / bf2f(d.z));
  r.w = f2bf(bf2f(s.w) * bf2f(nu.w) / bf2f(d.w));
  *(ushort4*)(y + i) = r;
}

// ---- LayerNorm over 1024, one row per block (256 thr x float4)
__global__ __launch_bounds__(256) void ln_k(const float* __restrict__ hbuf,
                                            const float* __restrict__ g,
                                            const float* __restrict__ bb,
                                            float* __restrict__ out) {
  __shared__ float red[16];
  const int row = blockIdx.x, t = threadIdx.x;
  const float4 hv = *(const float4*)(hbuf + (long)row * 1024 + t * 4);
  float s = hv.x + hv.y + hv.z + hv.w;
  float ss = hv.x * hv.x + hv.y * hv.y + hv.z * hv.z + hv.w * hv.w;
#pragma unroll
  for (int off = 32; off > 0; off >>= 1) {
    s += __shfl_down(s, off, 64);
    ss += __shfl_down(ss, off, 64);
  }
  const int wid = t >> 6;
  if ((t & 63) == 0) {
    red[wid] = s;
    red[8 + wid] = ss;
  }
  __syncthreads();
  const float tot = red[0] + red[1] + red[2] + red[3];
  const float tss = red[8] + red[9] + red[10] + red[11];
  const float mu = tot * (1.0f / 1024.0f);
  const float var = tss * (1.0f / 1024.0f) - mu * mu;
  const float rs = rsqrtf(var + 1e-5f);
  const float4 gv = *(const float4*)(g + t * 4);
  const float4 bv = *(const float4*)(bb + t * 4);
  float4 o;
  o.x = (hv.x - mu) * rs * gv.x + bv.x;
  o.y = (hv.y - mu) * rs * gv.y + bv.y;
  o.z = (hv.z - mu) * rs * gv.z + bv.z;
  o.w = (hv.w - mu) * rs * gv.w + bv.w;
  *(float4*)(out + (long)row * 1024 + t * 4) = o;
}

// ---------------------------------------------------------------------------
extern "C" void kernel_launch(void* const* d_in, const int* in_sizes, int n_in,
                              void* d_out, int out_size, void* d_ws, size_t ws_size,
                              hipStream_t stream) {
  (void)in_sizes; (void)n_in; (void)out_size; (void)ws_size;
  const float* x     = (const float*)d_in[0];
  const float* Wq_w  = (const float*)d_in[1];
  const float* Wq_b  = (const float*)d_in[2];
  const float* Wk_w  = (const float*)d_in[3];
  const float* Wk_b  = (const float*)d_in[4];
  const float* Wv_w  = (const float*)d_in[5];
  const float* Wv_b  = (const float*)d_in[6];
  const float* wbias = (const float*)d_in[7];
  const float* outw  = (const float*)d_in[8];
  const float* outb  = (const float*)d_in[9];
  const float* lng   = (const float*)d_in[10];
  const float* lnb   = (const float*)d_in[11];
  // d_in[12] = local_mask: recomputed from indices (|t-s|<=127), not read.
  float* out = (float*)d_out;
  char* ws = (char*)d_ws;

  // workspace layout (liveness-overlapped, peak ~116.5 MB):
  unsigned short* sq   = (unsigned short*)(ws + 0 * MBYTE);    // 16 MB
  unsigned short* ekF  = (unsigned short*)(ws + 16 * MBYTE);   // 16 MB (dead after t_ekv)
  unsigned short* denB = (unsigned short*)(ws + 16 * MBYTE);   // reuse (GEMM2 after t_ekv)
  unsigned short* vF   = (unsigned short*)(ws + 32 * MBYTE);   // 16 MB (dead after t_ekv)
  unsigned short* numB = (unsigned short*)(ws + 32 * MBYTE);   // reuse
  unsigned short* xT   = (unsigned short*)(ws + 48 * MBYTE);   // 16 MB (alive thru GEMM3)
  unsigned short* ekkT = (unsigned short*)(ws + 64 * MBYTE);   // 32 MB (dead after GEMM2)
  float* hbuf          = (float*)(ws + 64 * MBYTE);            // 32 MB (GEMM3 after GEMM2)
  unsigned short* y    = (unsigned short*)(ws + 96 * MBYTE);   // 16 MB
  unsigned short* Btp  = (unsigned short*)(ws + 112 * MBYTE);            // 384 KB
  float* biascat       = (float*)(ws + 112 * MBYTE + 393216);            // 3 KB (pad 4K)
  unsigned short* outwT= (unsigned short*)(ws + 112 * MBYTE + 397312);   // 2 MB
  unsigned short* ewm1 = (unsigned short*)(ws + 112 * MBYTE + 397312 + 2097152); // 2 MB
  float* Ssum          = (float*)(ws + 112 * MBYTE + 397312 + 2 * 2097152);      // 64 KB

  prep_weights<<<768, 256, 0, stream>>>(Wq_w, Wq_b, Wk_w, Wk_b, Wv_w, Wv_b, Btp, biascat);
  prep_ewm1<<<4096, 256, 0, stream>>>(wbias, ewm1);
  prep_outwT<<<dim3(32, 32), dim3(32, 8), 0, stream>>>(outw, outwT);
  zero_S<<<64, 256, 0, stream>>>(Ssum);
  transpose_x<<<dim3(128, 8, 8), dim3(32, 8), 0, stream>>>(x, xT);

  // GEMM1: qkv proj  [32768x256] @ Bt[768x256]
  gemm1_qkv<<<dim3(6, 256, 1), 256, 0, stream>>>(xT, Btp, biascat, sq, ekF, vF);

  transpose_ekv<<<dim3(32, 32, 8), dim3(32, 8), 0, stream>>>(ekF, vF, ekkT, Ssum);

  // GEMM2: banded attention  per n: [1024x1024 ewm1] @ Bt[2048x1024 (ek|ekv)^T] + S
  gemm2_attn<<<dim3(16, 8, 8), 256, 0, stream>>>(ewm1, ekkT, denB, numB, Ssum);

  combine_y<<<8192, 256, 0, stream>>>(sq, denB, numB, y);

  // GEMM3: out proj  [8192x1024] @ Bt[1024x1024 out_w^T]  (+bias +residual xT)
  gemm3_out<<<dim3(8, 64, 1), 256, 0, stream>>>(y, outwT, outb, xT, hbuf);

  ln_k<<<8192, 256, 0, stream>>>(hbuf, lng, lnb, out);
}

// Round 11
// 236.398 us; speedup vs baseline: 1.2191x; 1.0449x over previous
//
#include <hip/hip_runtime.h>

// ---------------------------------------------------------------------------
// AFT local attention, fused pipeline for MI355X (gfx950)
// B=8, F=256, L=1024, H=4, D=256, MODEL=1024, WIN=128
// Round 10: combine_y fused into GEMM2 (paired den/num cols, f32 ratio,
//           writes y directly). Grid (8,8,8), 48KB LDS, 2 blocks/CU.
// ---------------------------------------------------------------------------

typedef __attribute__((ext_vector_type(8))) short short8;
typedef __attribute__((ext_vector_type(4))) float f32x4;

#define MBYTE 1048576L

__device__ __forceinline__ unsigned short f2bf(float f) {
  unsigned u = __float_as_uint(f);
  unsigned r = (u + 0x7fff + ((u >> 16) & 1)) >> 16;  // RNE
  return (unsigned short)r;
}
__device__ __forceinline__ float bf2f(unsigned short s) {
  return __uint_as_float(((unsigned)s) << 16);
}

// ---- prep: Wq/Wk/Wv -> Bt[768][256] bf16 (already [d][c] = Bt layout), bias cat
__global__ void prep_weights(const float* __restrict__ Wq, const float* __restrict__ bq,
                             const float* __restrict__ Wk, const float* __restrict__ bk,
                             const float* __restrict__ Wv, const float* __restrict__ bv,
                             unsigned short* __restrict__ Btp, float* __restrict__ biascat) {
  int i = blockIdx.x * 256 + threadIdx.x;   // 768*256 exact
  int r = i >> 8, c = i & 255;
  const float* W = (r < 256) ? Wq : ((r < 512) ? Wk : Wv);
  int rr = r & 255;
  Btp[i] = f2bf(W[rr * 256 + c]);
  if (c == 0) {
    const float* bp = (r < 256) ? bq : ((r < 512) ? bk : bv);
    biascat[r] = bp[rr];
  }
}

// ---- prep: ewm1[t][s] = expm1(w_bias) inside band (|t-s|<=127), 0 outside.
// ew = 1 + ewm1 exactly; the "1" part is handled by the column-sum S.
__global__ void prep_ewm1(const float* __restrict__ wbias, unsigned short* __restrict__ ewm1) {
  int i = blockIdx.x * 256 + threadIdx.x;   // 1M exact
  int t = i >> 10, s = i & 1023;
  int d = t - s;
  float v = (d >= -127 && d <= 127) ? expm1f(wbias[i]) : 0.0f;
  ewm1[i] = f2bf(v);
}

// ---- prep: out_wT[mm][j] = bf16(out_w[j][mm])  (transpose 1024x1024)
__global__ void prep_outwT(const float* __restrict__ outw, unsigned short* __restrict__ outwT) {
  __shared__ float tle[32][33];
  int j0 = blockIdx.y * 32, m0 = blockIdx.x * 32;
  int tx = threadIdx.x;
  for (int r = threadIdx.y; r < 32; r += 8)
    tle[r][tx] = outw[(long)(j0 + r) * 1024 + m0 + tx];
  __syncthreads();
  for (int r = threadIdx.y; r < 32; r += 8)
    outwT[(long)(m0 + r) * 1024 + j0 + tx] = f2bf(tle[tx][r]);
}

// ---- zero the colsum accumulator S [8][2048] f32
__global__ void zero_S(float* __restrict__ S) {
  S[blockIdx.x * 256 + threadIdx.x] = 0.0f;
}

// ---- x[n][c][l][h] -> xT bf16 [n][l][h][c]  (= GEMM1 A rows m=(n,l,h), k=c;
//      also == _flatten(x) residual, row-major [8192][1024])
__global__ void transpose_x(const float* __restrict__ x, unsigned short* __restrict__ xT) {
  __shared__ float tle[32][33];
  int n = blockIdx.z;
  int c0 = blockIdx.y * 32, lh0 = blockIdx.x * 32;
  int tx = threadIdx.x;
  for (int r = threadIdx.y; r < 32; r += 8)
    tle[r][tx] = x[(long)n * 1048576 + (long)(c0 + r) * 4096 + lh0 + tx];
  __syncthreads();
  for (int r = threadIdx.y; r < 32; r += 8) {
    int lh = lh0 + r, c = c0 + tx;
    int l = lh >> 2, h = lh & 3;
    xT[(long)n * 1048576 + (long)l * 1024 + h * 256 + c] = f2bf(tle[tx][r]);
  }
}

// ---- ekF,vF [n][l][j] -> ekkT[n][2048][1024] (rows j = ek^T, 1024+j = (ek*v)^T)
//      + fused column-sums S[n][j2] = sum_l ekkT[n][j2][l]  (atomic partials)
__global__ void transpose_ekv(const unsigned short* __restrict__ ekF,
                              const unsigned short* __restrict__ vF,
                              unsigned short* __restrict__ ekkT,
                              float* __restrict__ S) {
  __shared__ unsigned short tEK[32][33];
  __shared__ unsigned short tEKV[32][33];
  __shared__ float red[2][8][32];
  int n = blockIdx.z;
  int l0 = blockIdx.y * 32, j0 = blockIdx.x * 32;
  int tx = threadIdx.x, ty = threadIdx.y;
  for (int r = ty; r < 32; r += 8) {
    long idx = (long)n * 1048576 + (long)(l0 + r) * 1024 + j0 + tx;
    unsigned short e = ekF[idx];
    unsigned short v = vF[idx];
    tEK[r][tx] = e;
    tEKV[r][tx] = f2bf(bf2f(e) * bf2f(v));
  }
  __syncthreads();
  for (int r = ty; r < 32; r += 8) {
    int j = j0 + r, l = l0 + tx;
    ekkT[(long)n * 2097152 + (long)j * 1024 + l] = tEK[tx][r];
    ekkT[(long)n * 2097152 + (long)(1024 + j) * 1024 + l] = tEKV[tx][r];
  }
  // colsum partials over l (first index of tEK/tEKV)
  float p0 = 0.f, p1 = 0.f;
#pragma unroll
  for (int q = 0; q < 4; q++) {
    p0 += bf2f(tEK[ty + q * 8][tx]);
    p1 += bf2f(tEKV[ty + q * 8][tx]);
  }
  red[0][ty][tx] = p0;
  red[1][ty][tx] = p1;
  __syncthreads();
  if (ty == 0) {
    float s0 = 0.f, s1 = 0.f;
#pragma unroll
    for (int q = 0; q < 8; q++) {
      s0 += red[0][q][tx];
      s1 += red[1][q][tx];
    }
    atomicAdd(&S[n * 2048 + j0 + tx], s0);
    atomicAdd(&S[n * 2048 + 1024 + j0 + tx], s1);
  }
}

// ---------------------------------------------------------------------------
// bf16 MFMA GEMM body, 128x128 tile, BK=64, global_load_lds staging (m97).
// A [M][K] row-major bf16, Bt [N][K] row-major bf16 (B transposed). 4 waves,
// each wave does a 64x64 quadrant = 4x4 fragments of 16x16x32.
// EPI 1: proj epilogue (sigmoid(q)/exp(k)/v, bf16, qkv-flat layout)
// EPI 3: output proj epilogue (+out_b + residual xT bf16, f32)
// ---------------------------------------------------------------------------
template <int EPI>
__device__ __forceinline__ void gemm_body(
    int bx, int by,
    const unsigned short* __restrict__ A, const unsigned short* __restrict__ Bt,
    int K, int lda, int ldb,
    const float* __restrict__ biascat,
    unsigned short* __restrict__ sq, unsigned short* __restrict__ ekF,
    unsigned short* __restrict__ vF,
    const float* __restrict__ outb, const unsigned short* __restrict__ xTr,
    float* __restrict__ hbuf) {
  __shared__ unsigned short As[128 * 64];  // 16 KB
  __shared__ unsigned short Bs[128 * 64];  // 16 KB
  const int m0 = by * 128, n0 = bx * 128;
  const int t = threadIdx.x, lane = t & 63;
  const int wrow = ((t >> 6) >> 1) * 64, wcol = ((t >> 6) & 1) * 64;

  f32x4 zero = {0.f, 0.f, 0.f, 0.f};
  f32x4 acc[4][4];
#pragma unroll
  for (int a = 0; a < 4; a++)
#pragma unroll
    for (int b = 0; b < 4; b++) acc[a][b] = zero;

  const int nK = K >> 6;
  for (int kt = 0; kt < nK; ++kt) {
    const int k0 = kt << 6;
#pragma unroll
    for (int i = 0; i < 4; i++) {
      const int e = (t + i * 256) * 8;
      const int r = e >> 6, kc = e & 63;
      __builtin_amdgcn_global_load_lds(
          (const __attribute__((address_space(1))) void*)(A + (long)(m0 + r) * lda + k0 + kc),
          (__attribute__((address_space(3))) void*)(As + e), 16, 0, 0);
    }
#pragma unroll
    for (int i = 0; i < 4; i++) {
      const int e = (t + i * 256) * 8;
      const int r = e >> 6, kc = e & 63;
      __builtin_amdgcn_global_load_lds(
          (const __attribute__((address_space(1))) void*)(Bt + (long)(n0 + r) * ldb + k0 + kc),
          (__attribute__((address_space(3))) void*)(Bs + e), 16, 0, 0);
    }
    __syncthreads();
#pragma unroll
    for (int ks = 0; ks < 2; ++ks) {
      short8 af[4], bfv[4];
      const int kk = ks * 32 + (lane >> 4) * 8;
#pragma unroll
      for (int fm = 0; fm < 4; fm++)
        af[fm] = *(const short8*)&As[(wrow + fm * 16 + (lane & 15)) * 64 + kk];
#pragma unroll
      for (int fn = 0; fn < 4; fn++)
        bfv[fn] = *(const short8*)&Bs[(wcol + fn * 16 + (lane & 15)) * 64 + kk];
#pragma unroll
      for (int fm = 0; fm < 4; fm++)
#pragma unroll
        for (int fn = 0; fn < 4; fn++)
          acc[fm][fn] =
              __builtin_amdgcn_mfma_f32_16x16x32_bf16(af[fm], bfv[fn], acc[fm][fn], 0, 0, 0);
    }
    __syncthreads();
  }

  // epilogue: C/D mapping col=lane&15, row=(lane>>4)*4+j  [m89-verified]
#pragma unroll
  for (int fm = 0; fm < 4; fm++) {
#pragma unroll
    for (int fn = 0; fn < 4; fn++) {
#pragma unroll
      for (int j = 0; j < 4; j++) {
        const int row = m0 + wrow + fm * 16 + ((lane >> 4) * 4 + j);
        const int col = n0 + wcol + fn * 16 + (lane & 15);
        float val = acc[fm][fn][j];
        if constexpr (EPI == 1) {
          val += biascat[col];
          const int n = row >> 12, l = (row >> 2) & 1023, h = row & 3;
          const long base = (long)n * 1048576 + (long)l * 1024 + h * 256;
          if (col < 256)
            sq[base + col] = f2bf(1.0f / (1.0f + __expf(-val)));
          else if (col < 512)
            ekF[base + (col - 256)] = f2bf(__expf(val));
          else
            vF[base + (col - 512)] = f2bf(val);
        } else {
          const long idx = (long)row * 1024 + col;
          hbuf[idx] = val + outb[col] + bf2f(xTr[idx]);  // xT == _flatten(x)
        }
      }
    }
  }
}

// GEMM1: grid (6,256). XCD swizzle: all 6 n-blocks of one m0 share bid%8 class
// (same XCD L2) so the A row-panel is fetched from HBM once per XCD, not 6x.
// bijection: bid=[0,1536) -> c=bid&7, q=bid>>3, bx=q%6, by=c+8*(q/6).
__global__ __launch_bounds__(256, 2) void gemm1_qkv(
    const unsigned short* __restrict__ A, const unsigned short* __restrict__ Bt,
    const float* __restrict__ biascat,
    unsigned short* __restrict__ sq, unsigned short* __restrict__ ekF,
    unsigned short* __restrict__ vF) {
  int bid = blockIdx.x + 6 * blockIdx.y;
  int c = bid & 7, q = bid >> 3;
  int bx = q % 6, by = c + 8 * (q / 6);
  gemm_body<1>(bx, by, A, Bt, 256, 256, 256,
               biascat, sq, ekF, vF, nullptr, nullptr, nullptr);
}

// ---------------------------------------------------------------------------
// GEMM2 + combine fused: banded attention with PAIRED den/num columns.
// Grid (8,8,8): bx = j-tile (128 of 1024), by = t-tile, z = n.
// Per block: A = ewm1[t-tile][k], Bek = ekkT rows j, Bev = ekkT rows 1024+j.
// accK = banded den part, accV = banded num part. Epilogue adds colsums S
// (the "1" of ew=1+ewm1) in f32 and writes y = sigmoid(q)*num/den directly.
// LDS 48 KB -> 2 blocks/CU; 512 blocks = 2/CU exactly.
// ---------------------------------------------------------------------------
__global__ __launch_bounds__(256, 2) void gemm2_attn(
    const unsigned short* __restrict__ ewm1, const unsigned short* __restrict__ ekkT,
    const unsigned short* __restrict__ sq, const float* __restrict__ Ssum,
    unsigned short* __restrict__ y) {
  __shared__ unsigned short As[128 * 64];   // 16 KB
  __shared__ unsigned short Bek[128 * 64];  // 16 KB
  __shared__ unsigned short Bev[128 * 64];  // 16 KB
  const int z = blockIdx.z;
  const unsigned short* Bb = ekkT + (long)z * 2097152;
  const int m0 = blockIdx.y * 128, n0 = blockIdx.x * 128;
  const int t = threadIdx.x, lane = t & 63;
  const int wrow = ((t >> 6) >> 1) * 64, wcol = ((t >> 6) & 1) * 64;

  f32x4 zero = {0.f, 0.f, 0.f, 0.f};
  f32x4 accK[4][4], accV[4][4];
#pragma unroll
  for (int a = 0; a < 4; a++)
#pragma unroll
    for (int b = 0; b < 4; b++) { accK[a][b] = zero; accV[a][b] = zero; }

  // band for rows t in [m0, m0+127]: s in [m0-127, m0+254]
  int sLo = m0 - 127; if (sLo < 0) sLo = 0;
  int sHi = m0 + 254; if (sHi > 1023) sHi = 1023;
  const int ktLo = sLo >> 6, ktHi = sHi >> 6;

  for (int kt = ktLo; kt <= ktHi; ++kt) {
    const int k0 = kt << 6;
#pragma unroll
    for (int i = 0; i < 4; i++) {
      const int e = (t + i * 256) * 8;
      const int r = e >> 6, kc = e & 63;
      __builtin_amdgcn_global_load_lds(
          (const __attribute__((address_space(1))) void*)(ewm1 + (long)(m0 + r) * 1024 + k0 + kc),
          (__attribute__((address_space(3))) void*)(As + e), 16, 0, 0);
      __builtin_amdgcn_global_load_lds(
          (const __attribute__((address_space(1))) void*)(Bb + (long)(n0 + r) * 1024 + k0 + kc),
          (__attribute__((address_space(3))) void*)(Bek + e), 16, 0, 0);
      __builtin_amdgcn_global_load_lds(
          (const __attribute__((address_space(1))) void*)(Bb + (long)(1024 + n0 + r) * 1024 + k0 + kc),
          (__attribute__((address_space(3))) void*)(Bev + e), 16, 0, 0);
    }
    __syncthreads();
#pragma unroll
    for (int ks = 0; ks < 2; ++ks) {
      short8 af[4], bk[4], bv[4];
      const int kk = ks * 32 + (lane >> 4) * 8;
#pragma unroll
      for (int fm = 0; fm < 4; fm++)
        af[fm] = *(const short8*)&As[(wrow + fm * 16 + (lane & 15)) * 64 + kk];
#pragma unroll
      for (int fn = 0; fn < 4; fn++) {
        bk[fn] = *(const short8*)&Bek[(wcol + fn * 16 + (lane & 15)) * 64 + kk];
        bv[fn] = *(const short8*)&Bev[(wcol + fn * 16 + (lane & 15)) * 64 + kk];
      }
#pragma unroll
      for (int fm = 0; fm < 4; fm++)
#pragma unroll
        for (int fn = 0; fn < 4; fn++) {
          accK[fm][fn] =
              __builtin_amdgcn_mfma_f32_16x16x32_bf16(af[fm], bk[fn], accK[fm][fn], 0, 0, 0);
          accV[fm][fn] =
              __builtin_amdgcn_mfma_f32_16x16x32_bf16(af[fm], bv[fn], accV[fm][fn], 0, 0, 0);
        }
    }
    __syncthreads();
  }

  // epilogue: y = sigmoid(q) * num / den, f32 ratio, bf16 store
#pragma unroll
  for (int fm = 0; fm < 4; fm++) {
#pragma unroll
    for (int fn = 0; fn < 4; fn++) {
#pragma unroll
      for (int j = 0; j < 4; j++) {
        const int row = m0 + wrow + fm * 16 + ((lane >> 4) * 4 + j);
        const int col = n0 + wcol + fn * 16 + (lane & 15);
        const float den = accK[fm][fn][j] + Ssum[z * 2048 + col];
        const float num = accV[fm][fn][j] + Ssum[z * 2048 + 1024 + col];
        const long idx = (long)z * 1048576 + (long)row * 1024 + col;
        const float s = bf2f(sq[idx]);
        y[idx] = f2bf(s * num / den);
      }
    }
  }
}

// GEMM3: grid (8,64). Swizzle: 8 n-blocks of one m0 share bid%8 class.
// bijection: bid=[0,512) -> c=bid&7, q=bid>>3, bx=q&7, by=8*c+(q>>3).
__global__ __launch_bounds__(256, 2) void gemm3_out(
    const unsigned short* __restrict__ A, const unsigned short* __restrict__ Bt,
    const float* __restrict__ outb, const unsigned short* __restrict__ xTr,
    float* __restrict__ hbuf) {
  int bid = blockIdx.x + 8 * blockIdx.y;
  int c = bid & 7, q = bid >> 3;
  int bx = q & 7, by = 8 * c + (q >> 3);
  gemm_body<3>(bx, by, A, Bt, 1024, 1024, 1024,
               nullptr, nullptr, nullptr, nullptr, outb, xTr, hbuf);
}

// ---- LayerNorm over 1024, one row per block (256 thr x float4)
__global__ __launch_bounds__(256) void ln_k(const float* __restrict__ hbuf,
                                            const float* __restrict__ g,
                                            const float* __restrict__ bb,
                                            float* __restrict__ out) {
  __shared__ float red[16];
  const int row = blockIdx.x, t = threadIdx.x;
  const float4 hv = *(const float4*)(hbuf + (long)row * 1024 + t * 4);
  float s = hv.x + hv.y + hv.z + hv.w;
  float ss = hv.x * hv.x + hv.y * hv.y + hv.z * hv.z + hv.w * hv.w;
#pragma unroll
  for (int off = 32; off > 0; off >>= 1) {
    s += __shfl_down(s, off, 64);
    ss += __shfl_down(ss, off, 64);
  }
  const int wid = t >> 6;
  if ((t & 63) == 0) {
    red[wid] = s;
    red[8 + wid] = ss;
  }
  __syncthreads();
  const float tot = red[0] + red[1] + red[2] + red[3];
  const float tss = red[8] + red[9] + red[10] + red[11];
  const float mu = tot * (1.0f / 1024.0f);
  const float var = tss * (1.0f / 1024.0f) - mu * mu;
  const float rs = rsqrtf(var + 1e-5f);
  const float4 gv = *(const float4*)(g + t * 4);
  const float4 bv = *(const float4*)(bb + t * 4);
  float4 o;
  o.x = (hv.x - mu) * rs * gv.x + bv.x;
  o.y = (hv.y - mu) * rs * gv.y + bv.y;
  o.z = (hv.z - mu) * rs * gv.z + bv.z;
  o.w = (hv.w - mu) * rs * gv.w + bv.w;
  *(float4*)(out + (long)row * 1024 + t * 4) = o;
}

// ---------------------------------------------------------------------------
extern "C" void kernel_launch(void* const* d_in, const int* in_sizes, int n_in,
                              void* d_out, int out_size, void* d_ws, size_t ws_size,
                              hipStream_t stream) {
  (void)in_sizes; (void)n_in; (void)out_size; (void)ws_size;
  const float* x     = (const float*)d_in[0];
  const float* Wq_w  = (const float*)d_in[1];
  const float* Wq_b  = (const float*)d_in[2];
  const float* Wk_w  = (const float*)d_in[3];
  const float* Wk_b  = (const float*)d_in[4];
  const float* Wv_w  = (const float*)d_in[5];
  const float* Wv_b  = (const float*)d_in[6];
  const float* wbias = (const float*)d_in[7];
  const float* outw  = (const float*)d_in[8];
  const float* outb  = (const float*)d_in[9];
  const float* lng   = (const float*)d_in[10];
  const float* lnb   = (const float*)d_in[11];
  // d_in[12] = local_mask: recomputed from indices (|t-s|<=127), not read.
  float* out = (float*)d_out;
  char* ws = (char*)d_ws;

  // workspace layout (liveness-overlapped):
  unsigned short* sq   = (unsigned short*)(ws + 0 * MBYTE);    // 16 MB (thru GEMM2)
  unsigned short* ekF  = (unsigned short*)(ws + 16 * MBYTE);   // 16 MB (dead after t_ekv)
  unsigned short* vF   = (unsigned short*)(ws + 32 * MBYTE);   // 16 MB (dead after t_ekv)
  unsigned short* xT   = (unsigned short*)(ws + 48 * MBYTE);   // 16 MB (alive thru GEMM3)
  unsigned short* ekkT = (unsigned short*)(ws + 64 * MBYTE);   // 32 MB (dead after GEMM2)
  float* hbuf          = (float*)(ws + 64 * MBYTE);            // 32 MB (GEMM3 after GEMM2)
  unsigned short* y    = (unsigned short*)(ws + 96 * MBYTE);   // 16 MB (GEMM2 -> GEMM3)
  unsigned short* Btp  = (unsigned short*)(ws + 112 * MBYTE);            // 384 KB
  float* biascat       = (float*)(ws + 112 * MBYTE + 393216);            // 3 KB (pad 4K)
  unsigned short* outwT= (unsigned short*)(ws + 112 * MBYTE + 397312);   // 2 MB
  unsigned short* ewm1 = (unsigned short*)(ws + 112 * MBYTE + 397312 + 2097152); // 2 MB
  float* Ssum          = (float*)(ws + 112 * MBYTE + 397312 + 2 * 2097152);      // 64 KB

  prep_weights<<<768, 256, 0, stream>>>(Wq_w, Wq_b, Wk_w, Wk_b, Wv_w, Wv_b, Btp, biascat);
  prep_ewm1<<<4096, 256, 0, stream>>>(wbias, ewm1);
  prep_outwT<<<dim3(32, 32), dim3(32, 8), 0, stream>>>(outw, outwT);
  zero_S<<<64, 256, 0, stream>>>(Ssum);
  transpose_x<<<dim3(128, 8, 8), dim3(32, 8), 0, stream>>>(x, xT);

  // GEMM1: qkv proj  [32768x256] @ Bt[768x256]
  gemm1_qkv<<<dim3(6, 256, 1), 256, 0, stream>>>(xT, Btp, biascat, sq, ekF, vF);

  transpose_ekv<<<dim3(32, 32, 8), dim3(32, 8), 0, stream>>>(ekF, vF, ekkT, Ssum);

  // GEMM2+combine: per n, banded [1024x1024 ewm1] @ {ek^T, ekv^T} -> y directly
  gemm2_attn<<<dim3(8, 8, 8), 256, 0, stream>>>(ewm1, ekkT, sq, Ssum, y);

  // GEMM3: out proj  [8192x1024] @ Bt[1024x1024 out_w^T]  (+bias +residual xT)
  gemm3_out<<<dim3(8, 64, 1), 256, 0, stream>>>(y, outwT, outb, xT, hbuf);

  ln_k<<<8192, 256, 0, stream>>>(hbuf, lng, lnb, out);
}

// Round 16
// 233.069 us; speedup vs baseline: 1.2365x; 1.0143x over previous
//
#include <hip/hip_runtime.h>

// ---------------------------------------------------------------------------
// AFT local attention, fused pipeline for MI355X (gfx950)
// B=8, F=256, L=1024, H=4, D=256, MODEL=1024, WIN=128
// Round 12: LDS-restaged VECTORIZED epilogue stores (ushort8, 16B/lane) for
//           gemm1 (48MB out) and gemm2 (16MB out); was 2B/lane scalar stores.
// ---------------------------------------------------------------------------

typedef __attribute__((ext_vector_type(8))) short short8;
typedef __attribute__((ext_vector_type(4))) float f32x4;

#define MBYTE 1048576L

__device__ __forceinline__ unsigned short f2bf(float f) {
  unsigned u = __float_as_uint(f);
  unsigned r = (u + 0x7fff + ((u >> 16) & 1)) >> 16;  // RNE
  return (unsigned short)r;
}
__device__ __forceinline__ float bf2f(unsigned short s) {
  return __uint_as_float(((unsigned)s) << 16);
}

// ---- prep: Wq/Wk/Wv -> Bt[768][256] bf16 (already [d][c] = Bt layout), bias cat
__global__ void prep_weights(const float* __restrict__ Wq, const float* __restrict__ bq,
                             const float* __restrict__ Wk, const float* __restrict__ bk,
                             const float* __restrict__ Wv, const float* __restrict__ bv,
                             unsigned short* __restrict__ Btp, float* __restrict__ biascat) {
  int i = blockIdx.x * 256 + threadIdx.x;   // 768*256 exact
  int r = i >> 8, c = i & 255;
  const float* W = (r < 256) ? Wq : ((r < 512) ? Wk : Wv);
  int rr = r & 255;
  Btp[i] = f2bf(W[rr * 256 + c]);
  if (c == 0) {
    const float* bp = (r < 256) ? bq : ((r < 512) ? bk : bv);
    biascat[r] = bp[rr];
  }
}

// ---- prep: ewm1[t][s] = expm1(w_bias) inside band (|t-s|<=127), 0 outside.
// ew = 1 + ewm1 exactly; the "1" part is handled by the column-sum S.
__global__ void prep_ewm1(const float* __restrict__ wbias, unsigned short* __restrict__ ewm1) {
  int i = blockIdx.x * 256 + threadIdx.x;   // 1M exact
  int t = i >> 10, s = i & 1023;
  int d = t - s;
  float v = (d >= -127 && d <= 127) ? expm1f(wbias[i]) : 0.0f;
  ewm1[i] = f2bf(v);
}

// ---- prep: out_wT[mm][j] = bf16(out_w[j][mm])  (transpose 1024x1024)
__global__ void prep_outwT(const float* __restrict__ outw, unsigned short* __restrict__ outwT) {
  __shared__ float tle[32][33];
  int j0 = blockIdx.y * 32, m0 = blockIdx.x * 32;
  int tx = threadIdx.x;
  for (int r = threadIdx.y; r < 32; r += 8)
    tle[r][tx] = outw[(long)(j0 + r) * 1024 + m0 + tx];
  __syncthreads();
  for (int r = threadIdx.y; r < 32; r += 8)
    outwT[(long)(m0 + r) * 1024 + j0 + tx] = f2bf(tle[tx][r]);
}

// ---- zero the colsum accumulator S [8][2048] f32
__global__ void zero_S(float* __restrict__ S) {
  S[blockIdx.x * 256 + threadIdx.x] = 0.0f;
}

// ---- x[n][c][l][h] -> xT bf16 [n][l][h][c]  (= GEMM1 A rows m=(n,l,h), k=c;
//      also == _flatten(x) residual, row-major [8192][1024])
__global__ void transpose_x(const float* __restrict__ x, unsigned short* __restrict__ xT) {
  __shared__ float tle[32][33];
  int n = blockIdx.z;
  int c0 = blockIdx.y * 32, lh0 = blockIdx.x * 32;
  int tx = threadIdx.x;
  for (int r = threadIdx.y; r < 32; r += 8)
    tle[r][tx] = x[(long)n * 1048576 + (long)(c0 + r) * 4096 + lh0 + tx];
  __syncthreads();
  for (int r = threadIdx.y; r < 32; r += 8) {
    int lh = lh0 + r, c = c0 + tx;
    int l = lh >> 2, h = lh & 3;
    xT[(long)n * 1048576 + (long)l * 1024 + h * 256 + c] = f2bf(tle[tx][r]);
  }
}

// ---- ekF,vF [n][l][j] -> ekkT[n][2048][1024] (rows j = ek^T, 1024+j = (ek*v)^T)
//      + fused column-sums S[n][j2] = sum_l ekkT[n][j2][l]  (atomic partials)
__global__ void transpose_ekv(const unsigned short* __restrict__ ekF,
                              const unsigned short* __restrict__ vF,
                              unsigned short* __restrict__ ekkT,
                              float* __restrict__ S) {
  __shared__ unsigned short tEK[32][33];
  __shared__ unsigned short tEKV[32][33];
  __shared__ float red[2][8][32];
  int n = blockIdx.z;
  int l0 = blockIdx.y * 32, j0 = blockIdx.x * 32;
  int tx = threadIdx.x, ty = threadIdx.y;
  for (int r = ty; r < 32; r += 8) {
    long idx = (long)n * 1048576 + (long)(l0 + r) * 1024 + j0 + tx;
    unsigned short e = ekF[idx];
    unsigned short v = vF[idx];
    tEK[r][tx] = e;
    tEKV[r][tx] = f2bf(bf2f(e) * bf2f(v));
  }
  __syncthreads();
  for (int r = ty; r < 32; r += 8) {
    int j = j0 + r, l = l0 + tx;
    ekkT[(long)n * 2097152 + (long)j * 1024 + l] = tEK[tx][r];
    ekkT[(long)n * 2097152 + (long)(1024 + j) * 1024 + l] = tEKV[tx][r];
  }
  // colsum partials over l (first index of tEK/tEKV)
  float p0 = 0.f, p1 = 0.f;
#pragma unroll
  for (int q = 0; q < 4; q++) {
    p0 += bf2f(tEK[ty + q * 8][tx]);
    p1 += bf2f(tEKV[ty + q * 8][tx]);
  }
  red[0][ty][tx] = p0;
  red[1][ty][tx] = p1;
  __syncthreads();
  if (ty == 0) {
    float s0 = 0.f, s1 = 0.f;
#pragma unroll
    for (int q = 0; q < 8; q++) {
      s0 += red[0][q][tx];
      s1 += red[1][q][tx];
    }
    atomicAdd(&S[n * 2048 + j0 + tx], s0);
    atomicAdd(&S[n * 2048 + 1024 + j0 + tx], s1);
  }
}

// ---------------------------------------------------------------------------
// GEMM1: qkv proj [32768x256] @ Bt[768x256], 128x128 tile, BK=64.
// Epilogue: sigmoid/exp/pass by column class (wave-uniform per block), bf16
// into padded LDS C-tile (stride 136 shorts -> 16B-aligned rows), then
// coalesced ushort8 stores (16B/lane). Output buffer per block is FIXED:
// bx 0,1 -> sq ; 2,3 -> ekF ; 4,5 -> vF ; column half = (bx&1)*128.
// XCD swizzle: all 6 n-blocks of one m0 share bid%8 class.
// ---------------------------------------------------------------------------
__global__ __launch_bounds__(256, 2) void gemm1_qkv(
    const unsigned short* __restrict__ A, const unsigned short* __restrict__ Bt,
    const float* __restrict__ biascat,
    unsigned short* __restrict__ sq, unsigned short* __restrict__ ekF,
    unsigned short* __restrict__ vF) {
  __shared__ unsigned short smem[128 * 136];  // 34 KB; As/Bs overlay first 32 KB
  unsigned short* As = smem;                  // 128*64
  unsigned short* Bs = smem + 8192;           // 128*64
  int bid = blockIdx.x + 6 * blockIdx.y;
  int c = bid & 7, q = bid >> 3;
  int bx = q % 6, by = c + 8 * (q / 6);
  const int m0 = by * 128, n0 = bx * 128;
  const int t = threadIdx.x, lane = t & 63;
  const int wrow = ((t >> 6) >> 1) * 64, wcol = ((t >> 6) & 1) * 64;

  f32x4 zero = {0.f, 0.f, 0.f, 0.f};
  f32x4 acc[4][4];
#pragma unroll
  for (int a = 0; a < 4; a++)
#pragma unroll
    for (int b = 0; b < 4; b++) acc[a][b] = zero;

  for (int kt = 0; kt < 4; ++kt) {  // K=256
    const int k0 = kt << 6;
#pragma unroll
    for (int i = 0; i < 4; i++) {
      const int e = (t + i * 256) * 8;
      const int r = e >> 6, kc = e & 63;
      __builtin_amdgcn_global_load_lds(
          (const __attribute__((address_space(1))) void*)(A + (long)(m0 + r) * 256 + k0 + kc),
          (__attribute__((address_space(3))) void*)(As + e), 16, 0, 0);
    }
#pragma unroll
    for (int i = 0; i < 4; i++) {
      const int e = (t + i * 256) * 8;
      const int r = e >> 6, kc = e & 63;
      __builtin_amdgcn_global_load_lds(
          (const __attribute__((address_space(1))) void*)(Bt + (long)(n0 + r) * 256 + k0 + kc),
          (__attribute__((address_space(3))) void*)(Bs + e), 16, 0, 0);
    }
    __syncthreads();
#pragma unroll
    for (int ks = 0; ks < 2; ++ks) {
      short8 af[4], bfv[4];
      const int kk = ks * 32 + (lane >> 4) * 8;
#pragma unroll
      for (int fm = 0; fm < 4; fm++)
        af[fm] = *(const short8*)&As[(wrow + fm * 16 + (lane & 15)) * 64 + kk];
#pragma unroll
      for (int fn = 0; fn < 4; fn++)
        bfv[fn] = *(const short8*)&Bs[(wcol + fn * 16 + (lane & 15)) * 64 + kk];
#pragma unroll
      for (int fm = 0; fm < 4; fm++)
#pragma unroll
        for (int fn = 0; fn < 4; fn++)
          acc[fm][fn] =
              __builtin_amdgcn_mfma_f32_16x16x32_bf16(af[fm], bfv[fn], acc[fm][fn], 0, 0, 0);
    }
    __syncthreads();  // also protects smem reuse as C-tile below
  }

  // epilogue math -> bf16 -> padded LDS C-tile (stride 136)
#pragma unroll
  for (int fm = 0; fm < 4; fm++) {
#pragma unroll
    for (int fn = 0; fn < 4; fn++) {
      const int colc = (n0 + wcol + fn * 16) >> 8;  // 0=q,1=k,2=v (uniform per frag)
#pragma unroll
      for (int j = 0; j < 4; j++) {
        const int rl = wrow + fm * 16 + ((lane >> 4) * 4 + j);
        const int cl = wcol + fn * 16 + (lane & 15);
        float val = acc[fm][fn][j] + biascat[n0 + cl];
        unsigned short o;
        if (colc == 0)
          o = f2bf(1.0f / (1.0f + __expf(-val)));
        else if (colc == 1)
          o = f2bf(__expf(val));
        else
          o = f2bf(val);
        smem[rl * 136 + cl] = o;
      }
    }
  }
  __syncthreads();

  // coalesced writeout: ushort8 per lane, 8 passes; dest buffer fixed by bx
  unsigned short* buf = (bx < 2) ? sq : ((bx < 4) ? ekF : vF);
  const int half = (bx & 1) * 128;
#pragma unroll
  for (int p = 0; p < 8; p++) {
    const int r = (t >> 4) + p * 16;
    short8 v = *(const short8*)&smem[r * 136 + (t & 15) * 8];
    *(short8*)&buf[(long)(m0 + r) * 256 + half + (t & 15) * 8] = v;
  }
}

// ---------------------------------------------------------------------------
// GEMM2 + combine fused: banded attention with PAIRED den/num columns.
// Grid (8,8,8): bx = j-tile (128 of 1024), by = t-tile, z = n.
// accK/accV = banded den/num parts; epilogue adds colsums S (the "1" of
// ew=1+ewm1) in f32, computes y = sigmoid(q)*num/den (bf16), restages in
// LDS, stores ushort8 coalesced. LDS 48 KB -> 2 blocks/CU (512 = 2/CU).
// ---------------------------------------------------------------------------
__global__ __launch_bounds__(256, 2) void gemm2_attn(
    const unsigned short* __restrict__ ewm1, const unsigned short* __restrict__ ekkT,
    const unsigned short* __restrict__ sq, const float* __restrict__ Ssum,
    unsigned short* __restrict__ y) {
  __shared__ unsigned short smem[24576];  // 48 KB; As/Bek/Bev, then C-tile (34KB)
  unsigned short* As = smem;              // 128*64
  unsigned short* Bek = smem + 8192;
  unsigned short* Bev = smem + 16384;
  const int z = blockIdx.z;
  const unsigned short* Bb = ekkT + (long)z * 2097152;
  const int m0 = blockIdx.y * 128, n0 = blockIdx.x * 128;
  const int t = threadIdx.x, lane = t & 63;
  const int wrow = ((t >> 6) >> 1) * 64, wcol = ((t >> 6) & 1) * 64;

  f32x4 zero = {0.f, 0.f, 0.f, 0.f};
  f32x4 accK[4][4], accV[4][4];
#pragma unroll
  for (int a = 0; a < 4; a++)
#pragma unroll
    for (int b = 0; b < 4; b++) { accK[a][b] = zero; accV[a][b] = zero; }

  // band for rows t in [m0, m0+127]: s in [m0-127, m0+254]
  int sLo = m0 - 127; if (sLo < 0) sLo = 0;
  int sHi = m0 + 254; if (sHi > 1023) sHi = 1023;
  const int ktLo = sLo >> 6, ktHi = sHi >> 6;

  for (int kt = ktLo; kt <= ktHi; ++kt) {
    const int k0 = kt << 6;
#pragma unroll
    for (int i = 0; i < 4; i++) {
      const int e = (t + i * 256) * 8;
      const int r = e >> 6, kc = e & 63;
      __builtin_amdgcn_global_load_lds(
          (const __attribute__((address_space(1))) void*)(ewm1 + (long)(m0 + r) * 1024 + k0 + kc),
          (__attribute__((address_space(3))) void*)(As + e), 16, 0, 0);
      __builtin_amdgcn_global_load_lds(
          (const __attribute__((address_space(1))) void*)(Bb + (long)(n0 + r) * 1024 + k0 + kc),
          (__attribute__((address_space(3))) void*)(Bek + e), 16, 0, 0);
      __builtin_amdgcn_global_load_lds(
          (const __attribute__((address_space(1))) void*)(Bb + (long)(1024 + n0 + r) * 1024 + k0 + kc),
          (__attribute__((address_space(3))) void*)(Bev + e), 16, 0, 0);
    }
    __syncthreads();
#pragma unroll
    for (int ks = 0; ks < 2; ++ks) {
      short8 af[4], bk[4], bv[4];
      const int kk = ks * 32 + (lane >> 4) * 8;
#pragma unroll
      for (int fm = 0; fm < 4; fm++)
        af[fm] = *(const short8*)&As[(wrow + fm * 16 + (lane & 15)) * 64 + kk];
#pragma unroll
      for (int fn = 0; fn < 4; fn++) {
        bk[fn] = *(const short8*)&Bek[(wcol + fn * 16 + (lane & 15)) * 64 + kk];
        bv[fn] = *(const short8*)&Bev[(wcol + fn * 16 + (lane & 15)) * 64 + kk];
      }
#pragma unroll
      for (int fm = 0; fm < 4; fm++)
#pragma unroll
        for (int fn = 0; fn < 4; fn++) {
          accK[fm][fn] =
              __builtin_amdgcn_mfma_f32_16x16x32_bf16(af[fm], bk[fn], accK[fm][fn], 0, 0, 0);
          accV[fm][fn] =
              __builtin_amdgcn_mfma_f32_16x16x32_bf16(af[fm], bv[fn], accV[fm][fn], 0, 0, 0);
        }
    }
    __syncthreads();  // also protects smem reuse as C-tile below
  }

  // epilogue: y = sigmoid(q) * num / den (f32 ratio) -> bf16 -> LDS C-tile
#pragma unroll
  for (int fm = 0; fm < 4; fm++) {
#pragma unroll
    for (int fn = 0; fn < 4; fn++) {
#pragma unroll
      for (int j = 0; j < 4; j++) {
        const int rl = wrow + fm * 16 + ((lane >> 4) * 4 + j);
        const int cl = wcol + fn * 16 + (lane & 15);
        const int col = n0 + cl;
        const float den = accK[fm][fn][j] + Ssum[z * 2048 + col];
        const float num = accV[fm][fn][j] + Ssum[z * 2048 + 1024 + col];
        const float s = bf2f(sq[(long)z * 1048576 + (long)(m0 + rl) * 1024 + col]);
        smem[rl * 136 + cl] = f2bf(s * num / den);
      }
    }
  }
  __syncthreads();

  // coalesced writeout
#pragma unroll
  for (int p = 0; p < 8; p++) {
    const int r = (t >> 4) + p * 16;
    short8 v = *(const short8*)&smem[r * 136 + (t & 15) * 8];
    *(short8*)&y[(long)z * 1048576 + (long)(m0 + r) * 1024 + n0 + (t & 15) * 8] = v;
  }
}

// ---------------------------------------------------------------------------
// GEMM3: out proj [8192x1024] @ outwT[1024x1024] (+out_b +residual xT), f32 out.
// Grid (8,64) with XCD swizzle (8 n-blocks of one m0 share bid%8 class).
// ---------------------------------------------------------------------------
__global__ __launch_bounds__(256, 2) void gemm3_out(
    const unsigned short* __restrict__ A, const unsigned short* __restrict__ Bt,
    const float* __restrict__ outb, const unsigned short* __restrict__ xTr,
    float* __restrict__ hbuf) {
  __shared__ unsigned short As[128 * 64];  // 16 KB
  __shared__ unsigned short Bs[128 * 64];  // 16 KB
  int bid = blockIdx.x + 8 * blockIdx.y;
  int c = bid & 7, q = bid >> 3;
  int bx = q & 7, by = 8 * c + (q >> 3);
  const int m0 = by * 128, n0 = bx * 128;
  const int t = threadIdx.x, lane = t & 63;
  const int wrow = ((t >> 6) >> 1) * 64, wcol = ((t >> 6) & 1) * 64;

  f32x4 zero = {0.f, 0.f, 0.f, 0.f};
  f32x4 acc[4][4];
#pragma unroll
  for (int a = 0; a < 4; a++)
#pragma unroll
    for (int b = 0; b < 4; b++) acc[a][b] = zero;

  for (int kt = 0; kt < 16; ++kt) {  // K=1024
    const int k0 = kt << 6;
#pragma unroll
    for (int i = 0; i < 4; i++) {
      const int e = (t + i * 256) * 8;
      const int r = e >> 6, kc = e & 63;
      __builtin_amdgcn_global_load_lds(
          (const __attribute__((address_space(1))) void*)(A + (long)(m0 + r) * 1024 + k0 + kc),
          (__attribute__((address_space(3))) void*)(As + e), 16, 0, 0);
    }
#pragma unroll
    for (int i = 0; i < 4; i++) {
      const int e = (t + i * 256) * 8;
      const int r = e >> 6, kc = e & 63;
      __builtin_amdgcn_global_load_lds(
          (const __attribute__((address_space(1))) void*)(Bt + (long)(n0 + r) * 1024 + k0 + kc),
          (__attribute__((address_space(3))) void*)(Bs + e), 16, 0, 0);
    }
    __syncthreads();
#pragma unroll
    for (int ks = 0; ks < 2; ++ks) {
      short8 af[4], bfv[4];
      const int kk = ks * 32 + (lane >> 4) * 8;
#pragma unroll
      for (int fm = 0; fm < 4; fm++)
        af[fm] = *(const short8*)&As[(wrow + fm * 16 + (lane & 15)) * 64 + kk];
#pragma unroll
      for (int fn = 0; fn < 4; fn++)
        bfv[fn] = *(const short8*)&Bs[(wcol + fn * 16 + (lane & 15)) * 64 + kk];
#pragma unroll
      for (int fm = 0; fm < 4; fm++)
#pragma unroll
        for (int fn = 0; fn < 4; fn++)
          acc[fm][fn] =
              __builtin_amdgcn_mfma_f32_16x16x32_bf16(af[fm], bfv[fn], acc[fm][fn], 0, 0, 0);
    }
    __syncthreads();
  }

#pragma unroll
  for (int fm = 0; fm < 4; fm++) {
#pragma unroll
    for (int fn = 0; fn < 4; fn++) {
#pragma unroll
      for (int j = 0; j < 4; j++) {
        const int row = m0 + wrow + fm * 16 + ((lane >> 4) * 4 + j);
        const int col = n0 + wcol + fn * 16 + (lane & 15);
        const long idx = (long)row * 1024 + col;
        hbuf[idx] = acc[fm][fn][j] + outb[col] + bf2f(xTr[idx]);  // xT == _flatten(x)
      }
    }
  }
}

// ---- LayerNorm over 1024, one row per block (256 thr x float4)
__global__ __launch_bounds__(256) void ln_k(const float* __restrict__ hbuf,
                                            const float* __restrict__ g,
                                            const float* __restrict__ bb,
                                            float* __restrict__ out) {
  __shared__ float red[16];
  const int row = blockIdx.x, t = threadIdx.x;
  const float4 hv = *(const float4*)(hbuf + (long)row * 1024 + t * 4);
  float s = hv.x + hv.y + hv.z + hv.w;
  float ss = hv.x * hv.x + hv.y * hv.y + hv.z * hv.z + hv.w * hv.w;
#pragma unroll
  for (int off = 32; off > 0; off >>= 1) {
    s += __shfl_down(s, off, 64);
    ss += __shfl_down(ss, off, 64);
  }
  const int wid = t >> 6;
  if ((t & 63) == 0) {
    red[wid] = s;
    red[8 + wid] = ss;
  }
  __syncthreads();
  const float tot = red[0] + red[1] + red[2] + red[3];
  const float tss = red[8] + red[9] + red[10] + red[11];
  const float mu = tot * (1.0f / 1024.0f);
  const float var = tss * (1.0f / 1024.0f) - mu * mu;
  const float rs = rsqrtf(var + 1e-5f);
  const float4 gv = *(const float4*)(g + t * 4);
  const float4 bv = *(const float4*)(bb + t * 4);
  float4 o;
  o.x = (hv.x - mu) * rs * gv.x + bv.x;
  o.y = (hv.y - mu) * rs * gv.y + bv.y;
  o.z = (hv.z - mu) * rs * gv.z + bv.z;
  o.w = (hv.w - mu) * rs * gv.w + bv.w;
  *(float4*)(out + (long)row * 1024 + t * 4) = o;
}

// ---------------------------------------------------------------------------
extern "C" void kernel_launch(void* const* d_in, const int* in_sizes, int n_in,
                              void* d_out, int out_size, void* d_ws, size_t ws_size,
                              hipStream_t stream) {
  (void)in_sizes; (void)n_in; (void)out_size; (void)ws_size;
  const float* x     = (const float*)d_in[0];
  const float* Wq_w  = (const float*)d_in[1];
  const float* Wq_b  = (const float*)d_in[2];
  const float* Wk_w  = (const float*)d_in[3];
  const float* Wk_b  = (const float*)d_in[4];
  const float* Wv_w  = (const float*)d_in[5];
  const float* Wv_b  = (const float*)d_in[6];
  const float* wbias = (const float*)d_in[7];
  const float* outw  = (const float*)d_in[8];
  const float* outb  = (const float*)d_in[9];
  const float* lng   = (const float*)d_in[10];
  const float* lnb   = (const float*)d_in[11];
  // d_in[12] = local_mask: recomputed from indices (|t-s|<=127), not read.
  float* out = (float*)d_out;
  char* ws = (char*)d_ws;

  // workspace layout (liveness-overlapped):
  unsigned short* sq   = (unsigned short*)(ws + 0 * MBYTE);    // 16 MB (thru GEMM2)
  unsigned short* ekF  = (unsigned short*)(ws + 16 * MBYTE);   // 16 MB (dead after t_ekv)
  unsigned short* vF   = (unsigned short*)(ws + 32 * MBYTE);   // 16 MB (dead after t_ekv)
  unsigned short* xT   = (unsigned short*)(ws + 48 * MBYTE);   // 16 MB (alive thru GEMM3)
  unsigned short* ekkT = (unsigned short*)(ws + 64 * MBYTE);   // 32 MB (dead after GEMM2)
  float* hbuf          = (float*)(ws + 64 * MBYTE);            // 32 MB (GEMM3 after GEMM2)
  unsigned short* y    = (unsigned short*)(ws + 96 * MBYTE);   // 16 MB (GEMM2 -> GEMM3)
  unsigned short* Btp  = (unsigned short*)(ws + 112 * MBYTE);            // 384 KB
  float* biascat       = (float*)(ws + 112 * MBYTE + 393216);            // 3 KB (pad 4K)
  unsigned short* outwT= (unsigned short*)(ws + 112 * MBYTE + 397312);   // 2 MB
  unsigned short* ewm1 = (unsigned short*)(ws + 112 * MBYTE + 397312 + 2097152); // 2 MB
  float* Ssum          = (float*)(ws + 112 * MBYTE + 397312 + 2 * 2097152);      // 64 KB

  prep_weights<<<768, 256, 0, stream>>>(Wq_w, Wq_b, Wk_w, Wk_b, Wv_w, Wv_b, Btp, biascat);
  prep_ewm1<<<4096, 256, 0, stream>>>(wbias, ewm1);
  prep_outwT<<<dim3(32, 32), dim3(32, 8), 0, stream>>>(outw, outwT);
  zero_S<<<64, 256, 0, stream>>>(Ssum);
  transpose_x<<<dim3(128, 8, 8), dim3(32, 8), 0, stream>>>(x, xT);

  // GEMM1: qkv proj  [32768x256] @ Bt[768x256]
  gemm1_qkv<<<dim3(6, 256, 1), 256, 0, stream>>>(xT, Btp, biascat, sq, ekF, vF);

  transpose_ekv<<<dim3(32, 32, 8), dim3(32, 8), 0, stream>>>(ekF, vF, ekkT, Ssum);

  // GEMM2+combine: per n, banded [1024x1024 ewm1] @ {ek^T, ekv^T} -> y directly
  gemm2_attn<<<dim3(8, 8, 8), 256, 0, stream>>>(ewm1, ekkT, sq, Ssum, y);

  // GEMM3: out proj  [8192x1024] @ Bt[1024x1024 out_w^T]  (+bias +residual xT)
  gemm3_out<<<dim3(8, 64, 1), 256, 0, stream>>>(y, outwT, outb, xT, hbuf);

  ln_k<<<8192, 256, 0, stream>>>(hbuf, lng, lnb, out);
}